// Round 4
// baseline (1198.596 us; speedup 1.0000x reference)
//
#include <hip/hip_runtime.h>

// ---------------- problem constants ----------------
constexpr int N = 100000;
constexpr int F = 512;
constexpr int H = 128;
constexpr int E = 1600000;
constexpr int C = 64;
constexpr float EPS = 1e-5f;
constexpr float NF = 100000.0f;     // number of nodes as float
constexpr float IBN = 0.999995000037f; // 1/sqrt(1+1e-5)

// ---------------- workspace layout (float offsets) ----------------
constexpr size_t OFF_HT   = 0;                     // [N,H] trans hidden, later x1 (in-place)
constexpr size_t OFF_HG   = 12800000;              // [N,H] graph hidden, later x2 (in-place)
constexpr size_t OFF_AGG  = 25600000;              // [N,H]; FIRST reused as gram partials, THEN gather output
constexpr size_t OFF_CNT  = 38400000;              // int[N] in-degree  (zeroed)
constexpr size_t OFF_S    = 38500000;              // [128] colsum (written by k2r)
constexpr size_t OFF_G    = 38500128;              // [128,128] gram (written by k2r)
constexpr size_t OFF_PTR  = 38516512;              // int[N] CSR bucket starts
constexpr size_t OFF_CUR  = 38616512;              // int[N] placement cursors
constexpr size_t OFF_BS   = 38716512;              // int[128] scan block offsets
constexpr size_t OFF_SROW = 38716640;              // int[E] sorted src rows
constexpr size_t OFF_SVAL = 40316640;              // float[E] sorted edge weights
constexpr size_t OFF_GWV  = 41916640;              // 3 x [128,256]: G@Wv, G@Wk, G@Wq
constexpr size_t OFF_KV   = OFF_GWV + 3 * 32768;   // [2,128,128] kv_raw
constexpr size_t OFF_KSUM = OFF_KV + 32768;        // [256]
constexpr size_t OFF_VSUM = OFF_KSUM + 256;        // [256]
constexpr size_t OFF_QSUM = OFF_VSUM + 256;        // [256]
constexpr size_t OFF_SC   = OFF_QSUM + 256;        // [4]
constexpr size_t OFF_B    = OFF_SC + 4;            // bf16 Bt2[256][128] (16384 floats used of 32768)
constexpr size_t OFF_CC   = OFF_B + 32768;         // [256]
constexpr size_t OFF_U    = OFF_CC + 256;          // [128,2]
constexpr size_t OFF_U0   = OFF_U + 256;           // [2] (+2 pad)
constexpr size_t OFF_BT   = OFF_U0 + 4;            // bf16[16 kt][1024 chunks][8] = 65536 floats

constexpr int NB1024 = (N + 1023) / 1024;          // 98 scan blocks
constexpr int NB_GRAM = (N + 255) / 256;           // 391 gram blocks
constexpr size_t SP_BASE = (size_t)NB_GRAM * 16384; // colsum partials offset inside agg

typedef __attribute__((ext_vector_type(8))) short short8;
typedef __attribute__((ext_vector_type(4))) float floatx4;

__device__ __forceinline__ float4 ld4(const float* p) {
  return *reinterpret_cast<const float4*>(p);
}
__device__ __forceinline__ void st4(float* p, float4 v) {
  *reinterpret_cast<float4*>(p) = v;
}
__device__ __forceinline__ unsigned short f2bf(float f) {
  unsigned u = __float_as_uint(f);
  u += 0x7fff + ((u >> 16) & 1);       // RNE
  return (unsigned short)(u >> 16);
}
__device__ __forceinline__ float bf2f(unsigned short h) {
  return __uint_as_float((unsigned)h << 16);
}
// async global->LDS 16B copy (per-lane global addr, wave-uniform LDS base; HW adds lane*16)
__device__ __forceinline__ void gl_lds16(const unsigned short* g, unsigned short* l) {
  __builtin_amdgcn_global_load_lds(
      (const __attribute__((address_space(1))) unsigned int*)g,
      (__attribute__((address_space(3))) unsigned int*)l, 16, 0, 0);
}

// ---------------- K0: pack Wt||Wg -> bf16 Bt in gload_lds tile order ----------------
// Per K-step kt (32 wide), tile = 1024 chunks of 16B (8 bf16).
// Logical chunk for (k,n): g=(k>>3)&3, chunk = g*256 + ((n + 2g) & 255), element e = k&7.
__global__ __launch_bounds__(256) void k0_cvt(const float* __restrict__ Wt,
    const float* __restrict__ Wg, unsigned short* __restrict__ Bt)
{
  const int idx = blockIdx.x * 256 + threadIdx.x;   // < 131072
  const int k = idx >> 8;       // 0..511
  const int n = idx & 255;      // 0..255
  float v = (n < 128) ? Wt[(size_t)k * H + n] : Wg[(size_t)k * H + (n - 128)];
  const int kt = k >> 5;            // 0..15
  const int g  = (k >> 3) & 3;      // 0..3
  const int e  = k & 7;
  const int chunk = g * 256 + ((n + 2 * g) & 255);
  Bt[(((size_t)kt * 1024 + chunk) << 3) + e] = f2bf(v);
}

// ---------------- K1: MFMA fused fc GEMMs, 3-deep counted-vmcnt pipeline ----------------
// 64 rows/block, 4 waves (2x2 over 64x256), BK=32, 16 K-steps, 3 LDS buffers.
// Steady state per step kt: issue B(kt+2) gload_lds -> vmcnt(4) -> cvt+ds_write A(kt+1)
// -> issue A(kt+2) reg loads -> lgkmcnt(0)+s_barrier (raw, NO vm drain) -> MFMA buf[kt].
// Loads get ~2 compute phases of latency tolerance; vmcnt never drains to 0 mid-loop.
__global__ __launch_bounds__(256, 2) void k1_mfma(
    const float* __restrict__ x, const unsigned short* __restrict__ Bt,
    const float* __restrict__ bt, const float* __restrict__ lng, const float* __restrict__ lnb,
    const float* __restrict__ bgv, const float* __restrict__ bng, const float* __restrict__ bnb,
    float* __restrict__ ht, float* __restrict__ hg)
{
  __shared__ __align__(16) union {
    struct { unsigned short A[3][64 * 40]; unsigned short B[3][8192]; } st; // 15360+49152=64512 B
    struct { float lns[64 * 132]; float mu[64]; float rs[64]; } ln;         // 34304 B
  } sm;
  const int t = threadIdx.x;
  const int lane = t & 63;
  const int w = t >> 6;
  const int rq = (w >> 1) * 32;     // wave row base: 0 / 32
  const int cq = (w & 1) * 128;     // wave col base: 0 / 128
  const int g = lane >> 4;          // 0..3
  const int m = lane & 15;
  const int M0 = blockIdx.x * 64;

  floatx4 acc[2][8];
#pragma unroll
  for (int rt = 0; rt < 2; ++rt)
#pragma unroll
    for (int ct = 0; ct < 8; ++ct) acc[rt][ct] = (floatx4){0.f, 0.f, 0.f, 0.f};

  // A staging: thread t covers row t>>2, 8 cols at (t&3)*8 within the 32-wide K slice
  const int srow = t >> 2;          // 0..63
  const int scol8 = (t & 3) * 8;    // 0,8,16,24
  const int grow = (M0 + srow < N) ? (M0 + srow) : (N - 1);
  const float* xp = x + (size_t)grow * F + scol8;

  // B fragment chunk base (g-rotated)
  const int mb = cq + m + 2 * g;    // + ct*16, & 255 at use

  unsigned short* const Abase = &sm.st.A[0][0];
  unsigned short* const Bbase = &sm.st.B[0][0];
  const int ldsw = (w << 6);        // wave's 64-chunk segment base

  float4 a0, a1;                    // A regs in flight (for step "current+2")

  // ---- prologue ----
  {
#pragma unroll
    for (int i = 0; i < 4; ++i)
      gl_lds16(Bt + (((size_t)(i * 256 + t)) << 3),
               Bbase + ((size_t)(i * 256 + ldsw) << 3));
    a0 = ld4(xp); a1 = ld4(xp + 4);
    asm volatile("s_waitcnt vmcnt(0)" ::: "memory");
    ushort4 p0, p1v;
    p0.x = f2bf(a0.x); p0.y = f2bf(a0.y); p0.z = f2bf(a0.z); p0.w = f2bf(a0.w);
    p1v.x = f2bf(a1.x); p1v.y = f2bf(a1.y); p1v.z = f2bf(a1.z); p1v.w = f2bf(a1.w);
    *(ushort4*)(Abase + srow * 40 + scol8) = p0;
    *(ushort4*)(Abase + srow * 40 + scol8 + 4) = p1v;
    // stage 1 (left outstanding across the barrier: 4 B + 2 A = 6)
#pragma unroll
    for (int i = 0; i < 4; ++i)
      gl_lds16(Bt + (((size_t)1024 + i * 256 + t) << 3),
               Bbase + 8192 + ((size_t)(i * 256 + ldsw) << 3));
    a0 = ld4(xp + 32); a1 = ld4(xp + 36);
    asm volatile("s_waitcnt lgkmcnt(0)\ns_barrier" ::: "memory");
  }

  int bc = 0, b1 = 1, b2 = 2;       // rotating buffer indices
  for (int kt = 0; kt < 14; ++kt) {
    // P1: issue B loads for kt+2 into buf b2
    {
      unsigned short* Bn = Bbase + b2 * 8192;
#pragma unroll
      for (int i = 0; i < 4; ++i)
        gl_lds16(Bt + (((size_t)(kt + 2) * 1024 + i * 256 + t) << 3),
                 Bn + ((size_t)(i * 256 + ldsw) << 3));
    }
    // P2: counted wait — drains everything except this step's 4 B loads.
    // Guarantees: buf b1's B (issued kt-1) + A regs (issued kt-1) have landed.
    asm volatile("s_waitcnt vmcnt(4)" ::: "memory");
    // P3: cvt + ds_write A for step kt+1 into buf b1
    {
      ushort4 p0, p1v;
      p0.x = f2bf(a0.x); p0.y = f2bf(a0.y); p0.z = f2bf(a0.z); p0.w = f2bf(a0.w);
      p1v.x = f2bf(a1.x); p1v.y = f2bf(a1.y); p1v.z = f2bf(a1.z); p1v.w = f2bf(a1.w);
      unsigned short* An = Abase + b1 * 2560;
      *(ushort4*)(An + srow * 40 + scol8) = p0;
      *(ushort4*)(An + srow * 40 + scol8 + 4) = p1v;
    }
    // P5: issue A reg loads for step kt+2
    a0 = ld4(xp + (kt + 2) * 32);
    a1 = ld4(xp + (kt + 2) * 32 + 4);
    // P6: ds_writes visible, then barrier (raw: vm stays outstanding)
    asm volatile("s_waitcnt lgkmcnt(0)\ns_barrier" ::: "memory");
    // P7: compute buf bc
    {
      const unsigned short* Ab = Abase + bc * 2560;
      const unsigned short* Bb = Bbase + bc * 8192;
      short8 af[2], bf[8];
#pragma unroll
      for (int rt = 0; rt < 2; ++rt)
        af[rt] = *(const short8*)(Ab + (rq + rt * 16 + m) * 40 + g * 8);
#pragma unroll
      for (int ct = 0; ct < 8; ++ct) {
        const int chunk = g * 256 + ((mb + ct * 16) & 255);
        bf[ct] = *(const short8*)(Bb + ((size_t)chunk << 3));
      }
      __builtin_amdgcn_s_setprio(1);
#pragma unroll
      for (int rt = 0; rt < 2; ++rt)
#pragma unroll
        for (int ct = 0; ct < 8; ++ct)
          acc[rt][ct] = __builtin_amdgcn_mfma_f32_16x16x32_bf16(af[rt], bf[ct], acc[rt][ct], 0, 0, 0);
      __builtin_amdgcn_s_setprio(0);
    }
    const int tmp = bc; bc = b1; b1 = b2; b2 = tmp;
  }
  // ---- tail: kt = 14 (drain, last A write), kt = 15 (pure compute) ----
  {
    asm volatile("s_waitcnt vmcnt(0)" ::: "memory");
    ushort4 p0, p1v;
    p0.x = f2bf(a0.x); p0.y = f2bf(a0.y); p0.z = f2bf(a0.z); p0.w = f2bf(a0.w);
    p1v.x = f2bf(a1.x); p1v.y = f2bf(a1.y); p1v.z = f2bf(a1.z); p1v.w = f2bf(a1.w);
    unsigned short* An = Abase + b1 * 2560;
    *(ushort4*)(An + srow * 40 + scol8) = p0;
    *(ushort4*)(An + srow * 40 + scol8 + 4) = p1v;
    asm volatile("s_waitcnt lgkmcnt(0)\ns_barrier" ::: "memory");
#pragma unroll
    for (int step = 0; step < 2; ++step) {   // computes buf bc then buf b1
      const int bi = (step == 0) ? bc : b1;
      const unsigned short* Ab = Abase + bi * 2560;
      const unsigned short* Bb = Bbase + bi * 8192;
      short8 af[2], bf[8];
#pragma unroll
      for (int rt = 0; rt < 2; ++rt)
        af[rt] = *(const short8*)(Ab + (rq + rt * 16 + m) * 40 + g * 8);
#pragma unroll
      for (int ct = 0; ct < 8; ++ct) {
        const int chunk = g * 256 + ((mb + ct * 16) & 255);
        bf[ct] = *(const short8*)(Bb + ((size_t)chunk << 3));
      }
      __builtin_amdgcn_s_setprio(1);
#pragma unroll
      for (int rt = 0; rt < 2; ++rt)
#pragma unroll
        for (int ct = 0; ct < 8; ++ct)
          acc[rt][ct] = __builtin_amdgcn_mfma_f32_16x16x32_bf16(af[rt], bf[ct], acc[rt][ct], 0, 0, 0);
      __builtin_amdgcn_s_setprio(0);
    }
  }
  __syncthreads();   // all LDS reads done before the ln union overwrites st

  // epilogue. C/D layout: col = m, row = g*4 + reg
  if (cq == 0) {
#pragma unroll
    for (int rt = 0; rt < 2; ++rt)
#pragma unroll
      for (int ct = 0; ct < 8; ++ct) {
        const int col = ct * 16 + m;
        const float b = bt[col];
#pragma unroll
        for (int r = 0; r < 4; ++r)
          sm.ln.lns[(rq + rt * 16 + g * 4 + r) * 132 + col] = acc[rt][ct][r] + b;
      }
  } else {
#pragma unroll
    for (int rt = 0; rt < 2; ++rt)
#pragma unroll
      for (int ct = 0; ct < 8; ++ct) {
        const int col = ct * 16 + m;
        const float s1 = IBN * bng[col], b0 = bgv[col], b2v = bnb[col];
#pragma unroll
        for (int r = 0; r < 4; ++r) {
          const int row = M0 + rq + rt * 16 + g * 4 + r;
          if (row < N) {
            float v = (acc[rt][ct][r] + b0) * s1 + b2v;
            hg[(size_t)row * H + col] = v > 0.f ? v : 0.f;
          }
        }
      }
  }
  __syncthreads();
  if (t < 64) {
    float sum = 0.f, sq = 0.f;
    for (int c2 = 0; c2 < H; ++c2) {
      float v = sm.ln.lns[t * 132 + c2];
      sum += v; sq += v * v;
    }
    float mu = sum * (1.f / H);
    float var = sq * (1.f / H) - mu * mu;
    sm.ln.mu[t] = mu; sm.ln.rs[t] = rsqrtf(var + EPS);
  }
  __syncthreads();
  {
    const int r = t >> 2;
    const int cb = (t & 3) * 32;
    if (M0 + r < N) {
      const float mu = sm.ln.mu[r], rs = sm.ln.rs[r];
#pragma unroll
      for (int j = 0; j < 8; ++j) {
        const int c = cb + j * 4;
        float o[4];
#pragma unroll
        for (int q = 0; q < 4; ++q) {
          float v = (sm.ln.lns[r * 132 + c + q] - mu) * rs * lng[c + q] + lnb[c + q];
          o[q] = v > 0.f ? v : 0.f;
        }
        st4(ht + (size_t)(M0 + r) * H + c, make_float4(o[0], o[1], o[2], o[3]));
      }
    }
  }
}

// ---------------- K2: gram + colsum partials, NO atomics ----------------
__global__ __launch_bounds__(256) void k2_gram(const float* __restrict__ ht,
                                               float* __restrict__ gp,   // [NB_GRAM][16384]
                                               float* __restrict__ sp)   // [NB_GRAM][128]
{
  const int t = threadIdx.x;
  const int b = blockIdx.x;
  const int base = b * 256;
  const int nend = (base + 256 < N) ? base + 256 : N;
  const int r0 = (t >> 4) * 8;
  const int c0 = (t & 15) * 8;
  float acc[8][8] = {};
  float colacc[8] = {};
  const bool do_col = (t < 16);
  int n = base;
  for (; n + 1 < nend; n += 2) {
    const float* hp0 = ht + (size_t)n * H;
    const float* hp1 = hp0 + H;
    float4 a00 = ld4(hp0 + r0), a01 = ld4(hp0 + r0 + 4);
    float4 b00 = ld4(hp0 + c0), b01 = ld4(hp0 + c0 + 4);
    float4 a10 = ld4(hp1 + r0), a11 = ld4(hp1 + r0 + 4);
    float4 b10 = ld4(hp1 + c0), b11 = ld4(hp1 + c0 + 4);
    float a0[8] = {a00.x, a00.y, a00.z, a00.w, a01.x, a01.y, a01.z, a01.w};
    float b0[8] = {b00.x, b00.y, b00.z, b00.w, b01.x, b01.y, b01.z, b01.w};
    float a1[8] = {a10.x, a10.y, a10.z, a10.w, a11.x, a11.y, a11.z, a11.w};
    float b1[8] = {b10.x, b10.y, b10.z, b10.w, b11.x, b11.y, b11.z, b11.w};
    if (do_col) {
#pragma unroll
      for (int j = 0; j < 8; ++j) colacc[j] += b0[j] + b1[j];
    }
#pragma unroll
    for (int i = 0; i < 8; ++i)
#pragma unroll
      for (int j = 0; j < 8; ++j)
        acc[i][j] += a0[i] * b0[j] + a1[i] * b1[j];
  }
  if (n < nend) {
    const float* hp0 = ht + (size_t)n * H;
    float4 a00 = ld4(hp0 + r0), a01 = ld4(hp0 + r0 + 4);
    float4 b00 = ld4(hp0 + c0), b01 = ld4(hp0 + c0 + 4);
    float a0[8] = {a00.x, a00.y, a00.z, a00.w, a01.x, a01.y, a01.z, a01.w};
    float b0[8] = {b00.x, b00.y, b00.z, b00.w, b01.x, b01.y, b01.z, b01.w};
    if (do_col) {
#pragma unroll
      for (int j = 0; j < 8; ++j) colacc[j] += b0[j];
    }
#pragma unroll
    for (int i = 0; i < 8; ++i)
#pragma unroll
      for (int j = 0; j < 8; ++j)
        acc[i][j] += a0[i] * b0[j];
  }
  float* g = gp + (size_t)b * 16384;
#pragma unroll
  for (int i = 0; i < 8; ++i) {
    st4(&g[(r0 + i) * H + c0], make_float4(acc[i][0], acc[i][1], acc[i][2], acc[i][3]));
    st4(&g[(r0 + i) * H + c0 + 4], make_float4(acc[i][4], acc[i][5], acc[i][6], acc[i][7]));
  }
  if (do_col) {
    float* spb = sp + (size_t)b * 128;
    st4(&spb[c0], make_float4(colacc[0], colacc[1], colacc[2], colacc[3]));
    st4(&spb[c0 + 4], make_float4(colacc[4], colacc[5], colacc[6], colacc[7]));
  }
}

// ---------------- K2r: reduce partials -> G, s ----------------
__global__ __launch_bounds__(256) void k2r_reduce(const float* __restrict__ gp,
    const float* __restrict__ sp, float* __restrict__ G, float* __restrict__ s)
{
  const int i = blockIdx.x * 256 + threadIdx.x;   // < 16384
  float s0 = 0.f, s1 = 0.f, s2 = 0.f, s3 = 0.f;
  int b = 0;
  for (; b + 3 < NB_GRAM; b += 4) {
    s0 += gp[(size_t)b * 16384 + i];
    s1 += gp[(size_t)(b + 1) * 16384 + i];
    s2 += gp[(size_t)(b + 2) * 16384 + i];
    s3 += gp[(size_t)(b + 3) * 16384 + i];
  }
  for (; b < NB_GRAM; ++b) s0 += gp[(size_t)b * 16384 + i];
  G[i] = (s0 + s1) + (s2 + s3);
  if (blockIdx.x == 0 && threadIdx.x < 128) {
    float t0 = 0.f, t1 = 0.f;
    int bb = 0;
    for (; bb + 1 < NB_GRAM; bb += 2) {
      t0 += sp[(size_t)bb * 128 + threadIdx.x];
      t1 += sp[(size_t)(bb + 1) * 128 + threadIdx.x];
    }
    for (; bb < NB_GRAM; ++bb) t0 += sp[(size_t)bb * 128 + threadIdx.x];
    s[threadIdx.x] = t0 + t1;
  }
}

// ---------------- K3a: GW = G @ {Wv, Wk, Wq} ----------------
__global__ __launch_bounds__(256) void k3a_gw(const float* __restrict__ G,
    const float* __restrict__ Wv, const float* __restrict__ Wk,
    const float* __restrict__ Wq, float* __restrict__ GW)
{
  const int flat = blockIdx.x * 256 + threadIdx.x;   // < 98304
  const int w = flat >> 15;
  const int rem = flat & 32767;
  const int i = rem >> 8;
  const int j = rem & 255;
  const float* W = (w == 0) ? Wv : (w == 1) ? Wk : Wq;
  float sum = 0.f;
#pragma unroll 8
  for (int k = 0; k < H; ++k) sum += G[i * H + k] * W[k * 256 + j];
  GW[flat] = sum;
}

// ---------------- K3k: ksum/vsum/qsum = s @ W + N*b ----------------
__global__ __launch_bounds__(256) void k3k_sums(const float* __restrict__ s,
    const float* __restrict__ Wk, const float* __restrict__ bk,
    const float* __restrict__ Wv, const float* __restrict__ bv,
    const float* __restrict__ Wq, const float* __restrict__ bq,
    float* __restrict__ ksum, float* __restrict__ vsum, float* __restrict__ qsum)
{
  const int flat = blockIdx.x * 256 + threadIdx.x;   // < 768
  const int w = flat >> 8;
  const int j = flat & 255;
  const float* W = (w == 0) ? Wk : (w == 1) ? Wv : Wq;
  const float* b = (w == 0) ? bk : (w == 1) ? bv : bq;
  float* out = (w == 0) ? ksum : (w == 1) ? vsum : qsum;
  float sum = 0.f;
#pragma unroll 8
  for (int k = 0; k < H; ++k) sum += s[k] * W[k * 256 + j];
  out[j] = sum + NF * b[j];
}

// ---------------- K3b: kv_raw[h,m,d] ----------------
__global__ __launch_bounds__(256) void k3b_kv(const float* __restrict__ GWv,
    const float* __restrict__ s, const float* __restrict__ Wk,
    const float* __restrict__ bk, const float* __restrict__ bv,
    const float* __restrict__ vsum, float* __restrict__ kv)
{
  const int flat = blockIdx.x * 256 + threadIdx.x;   // < 32768
  const int h = flat >> 14;
  const int m = (flat >> 7) & 127;
  const int d = flat & 127;
  float s1 = 0.f, s2 = 0.f;
#pragma unroll 4
  for (int k = 0; k < H; ++k) {
    float wkv = Wk[k * 256 + h * 128 + m];
    s1 += wkv * GWv[k * 256 + h * 128 + d];
    s2 += wkv * s[k];
  }
  kv[flat] = s1 + s2 * bv[h * 128 + d] + bk[h * 128 + m] * vsum[h * 128 + d];
}

// ---------------- K3c: ssq_q, ssq_k, inv ----------------
__global__ __launch_bounds__(256) void k3c_ssq(
    const float* __restrict__ Wk, const float* __restrict__ GWk,
    const float* __restrict__ Wq, const float* __restrict__ GWq,
    const float* __restrict__ bk, const float* __restrict__ ksum,
    const float* __restrict__ bq, const float* __restrict__ qsum,
    float* __restrict__ sc)
{
  __shared__ float red[512];
  const int t = threadIdx.x;
  float pk = 0.f, pq = 0.f;
  for (int i = t; i < 32768; i += 256) {
    pk += Wk[i] * GWk[i];
    pq += Wq[i] * GWq[i];
  }
  pk += 2.f * bk[t] * ksum[t] - NF * bk[t] * bk[t];
  pq += 2.f * bq[t] * qsum[t] - NF * bq[t] * bq[t];
  red[t] = pk; red[256 + t] = pq;
  __syncthreads();
  for (int off = 128; off > 0; off >>= 1) {
    if (t < off) { red[t] += red[t + off]; red[256 + t] += red[256 + t + off]; }
    __syncthreads();
  }
  if (t == 0) {
    float ssq_k = red[0], ssq_q = red[256];
    sc[0] = ssq_q; sc[1] = ssq_k;
    sc[2] = rsqrtf(ssq_q * ssq_k);   // 1/(||q|| * ||k||)
  }
}

// ---------------- K3d: B = Wq @ kv * inv + N*Wv -> packed bf16 Bt2[n=256][k=128] ----------------
__global__ __launch_bounds__(256) void k3d_B(const float* __restrict__ Wq,
    const float* __restrict__ kv, const float* __restrict__ Wv,
    const float* __restrict__ sc, unsigned short* __restrict__ Bt2)
{
  const int flat = blockIdx.x * 256 + threadIdx.x;   // < 32768
  const int i = flat >> 8;       // 0..127 : k-dim (h index)
  const int j = flat & 255;      // 0..255 : col (head*128 + d)
  const int h = j >> 7;
  const int d = j & 127;
  const float inv = sc[2];
  float sum = 0.f;
#pragma unroll 4
  for (int m = 0; m < H; ++m)
    sum += Wq[i * 256 + h * 128 + m] * kv[h * 16384 + m * 128 + d];
  Bt2[(size_t)j * H + i] = f2bf(sum * inv + NF * Wv[i * 256 + j]);
}

// ---------------- K3e: c, u, u0 ----------------
__global__ __launch_bounds__(512) void k3e_small(const float* __restrict__ bq,
    const float* __restrict__ kv, const float* __restrict__ bv,
    const float* __restrict__ Wq, const float* __restrict__ ksum,
    const float* __restrict__ sc, float* __restrict__ cc,
    float* __restrict__ u, float* __restrict__ u0)
{
  const int t = threadIdx.x;
  const float inv = sc[2];
  if (t < 256) {
    const int h = t >> 7, d = t & 127;
    float sum = 0.f;
    for (int m = 0; m < H; ++m) sum += bq[h * 128 + m] * kv[h * 16384 + m * 128 + d];
    cc[t] = sum * inv + NF * bv[t];
  } else {
    const int q = t - 256;
    const int i = q >> 1, h = q & 1;
    float sum = 0.f;
    for (int m = 0; m < H; ++m) sum += Wq[i * 256 + h * 128 + m] * ksum[h * 128 + m];
    u[i * 2 + h] = sum * inv;
  }
  if (t < 2) {
    float sum = 0.f;
    for (int m = 0; m < H; ++m) sum += bq[t * 128 + m] * ksum[t * 128 + m];
    u0[t] = sum * inv + NF;
  }
}

// ---------------- K4: MFMA attention apply + residual + LN -> x1 (in-place in ht) ----------------
// 64-row tile; 4 waves; each wave: 16 rows x all 256 cols (head combine is in-lane: ct vs ct+8)
__global__ __launch_bounds__(256) void k4_mfma(float* __restrict__ ht,
    const unsigned short* __restrict__ Bt2, const float* __restrict__ cc,
    const float* __restrict__ u, const float* __restrict__ u0,
    const float* __restrict__ lng, const float* __restrict__ lnb)
{
  __shared__ __align__(16) union {
    unsigned short A[64 * 136];       // 17408 B (bf16 ht tile)
    float lns[64 * 132];              // 33792 B (LN staging)
  } sm;
  __shared__ float u_s[256];
  __shared__ float rden_s[128];       // [row][head]
  __shared__ float mu_s[64], rs_s[64];
  const int t = threadIdx.x;
  const int lane = t & 63;
  const int w = t >> 6;
  const int rq = w * 16;              // wave row base 0/16/32/48
  const int g = lane >> 4;
  const int m = lane & 15;
  const int M0 = blockIdx.x * 64;

  // stage A: ht rows fp32 -> bf16 LDS (K=128 fits entirely)
  {
    const int srow = t >> 2;          // 0..63
    const int scol = (t & 3) * 32;    // 0,32,64,96
    const int grow = (M0 + srow < N) ? (M0 + srow) : (N - 1);
    const float* xp = ht + (size_t)grow * H + scol;
#pragma unroll
    for (int j = 0; j < 8; ++j) {
      float4 a4 = ld4(xp + j * 4);
      ushort4 p;
      p.x = f2bf(a4.x); p.y = f2bf(a4.y); p.z = f2bf(a4.z); p.w = f2bf(a4.w);
      *(ushort4*)(sm.A + srow * 136 + scol + j * 4) = p;
    }
  }
  u_s[t] = u[t];
  __syncthreads();

  floatx4 acc[16];
#pragma unroll
  for (int ct = 0; ct < 16; ++ct) acc[ct] = (floatx4){0.f, 0.f, 0.f, 0.f};
#pragma unroll
  for (int kk = 0; kk < 128; kk += 32) {
    short8 af = *(const short8*)(sm.A + (rq + m) * 136 + kk + g * 8);
#pragma unroll
    for (int ct = 0; ct < 16; ++ct) {
      short8 bf = *(const short8*)(Bt2 + (size_t)(ct * 16 + m) * H + kk + g * 8);
      acc[ct] = __builtin_amdgcn_mfma_f32_16x16x32_bf16(af, bf, acc[ct], 0, 0, 0);
    }
  }
  // denominators (waves 0,1): row=t>>1, head=t&1
  if (t < 128) {
    const int row = t >> 1, head = t & 1;
    float den = u0[head];
    for (int k = 0; k < H; ++k)
      den += bf2f(sm.A[row * 136 + k]) * u_s[k * 2 + head];
    rden_s[row * 2 + head] = 0.5f / den;   // mean-over-heads folded
  }
  __syncthreads();   // A fully consumed; lns may now overwrite the union

  // combine heads + residual -> lns
#pragma unroll
  for (int ct = 0; ct < 8; ++ct) {
    const int d = ct * 16 + m;
    const float c0v = cc[d], c1v = cc[128 + d];
#pragma unroll
    for (int r = 0; r < 4; ++r) {
      const int row = rq + g * 4 + r;         // block-local 0..63
      const int grow = M0 + row;
      const float rd0 = rden_s[row * 2], rd1 = rden_s[row * 2 + 1];
      float attn = (acc[ct][r] + c0v) * rd0 + (acc[ct + 8][r] + c1v) * rd1;
      float hres = (grow < N) ? ht[(size_t)grow * H + d] : 0.f;
      sm.lns[row * 132 + d] = (attn + hres) * 0.5f;
    }
  }
  __syncthreads();
  if (t < 64) {
    float sum = 0.f, sq = 0.f;
    for (int c2 = 0; c2 < H; ++c2) {
      float v = sm.lns[t * 132 + c2];
      sum += v; sq += v * v;
    }
    float mu = sum * (1.f / H);
    float var = sq * (1.f / H) - mu * mu;
    mu_s[t] = mu; rs_s[t] = rsqrtf(var + EPS);
  }
  __syncthreads();
  {
    const int r = t >> 2;
    const int cb = (t & 3) * 32;
    if (M0 + r < N) {
      const float mu = mu_s[r], rs = rs_s[r];
#pragma unroll
      for (int j = 0; j < 8; ++j) {
        const int c = cb + j * 4;
        float o[4];
#pragma unroll
        for (int q = 0; q < 4; ++q) {
          float v = (sm.lns[r * 132 + c + q] - mu) * rs * lng[c + q] + lnb[c + q];
          o[q] = v > 0.f ? v : 0.f;
        }
        st4(ht + (size_t)(M0 + r) * H + c, make_float4(o[0], o[1], o[2], o[3]));
      }
    }
  }
}

// ---------------- K5: in-degree (int counts) ----------------
__global__ __launch_bounds__(256) void k5_deg(const int* __restrict__ ei,
                                              int* __restrict__ cnt)
{
  const int i = blockIdx.x * 256 + threadIdx.x;
  if (i < E) atomicAdd(&cnt[ei[E + i]], 1);
}

// ---------------- scan1: per-1024-chunk sums ----------------
__global__ __launch_bounds__(256) void k_scan1(const int* __restrict__ cnt,
                                               int* __restrict__ bsum)
{
  __shared__ int red[256];
  const int t = threadIdx.x;
  const int base = blockIdx.x * 1024 + t * 4;
  int s = 0;
#pragma unroll
  for (int j = 0; j < 4; ++j) {
    int idx = base + j;
    if (idx < N) s += cnt[idx];
  }
  red[t] = s;
  __syncthreads();
  for (int off = 128; off > 0; off >>= 1) {
    if (t < off) red[t] += red[t + off];
    __syncthreads();
  }
  if (t == 0) bsum[blockIdx.x] = red[0];
}

// ---------------- scan2: serial exclusive scan of 98 block sums ----------------
__global__ void k_scan2(int* __restrict__ bsum)
{
  if (threadIdx.x == 0 && blockIdx.x == 0) {
    int run = 0;
    for (int b = 0; b < NB1024; ++b) {
      int v = bsum[b];
      bsum[b] = run;
      run += v;
    }
  }
}

// ---------------- scan3: intra-chunk exclusive scan -> ptr, cur ----------------
__global__ __launch_bounds__(256) void k_scan3(const int* __restrict__ cnt,
    const int* __restrict__ bsum, int* __restrict__ ptr, int* __restrict__ cur)
{
  __shared__ int part[256];
  const int t = threadIdx.x;
  const int base = blockIdx.x * 1024 + t * 4;
  int v[4];
  int tsum = 0;
#pragma unroll
  for (int j = 0; j < 4; ++j) {
    int idx = base + j;
    v[j] = (idx < N) ? cnt[idx] : 0;
    tsum += v[j];
  }
  part[t] = tsum;
  __syncthreads();
  for (int off = 1; off < 256; off <<= 1) {
    int add = (t >= off) ? part[t - off] : 0;
    __syncthreads();
    part[t] += add;
    __syncthreads();
  }
  int run = bsum[blockIdx.x] + part[t] - tsum;
#pragma unroll
  for (int j = 0; j < 4; ++j) {
    int idx = base + j;
    if (idx < N) { ptr[idx] = run; cur[idx] = run; }
    run += v[j];
  }
}

// ---------------- K6a: place edges into destination buckets ----------------
__global__ __launch_bounds__(256) void k6a_place(const int* __restrict__ ei,
    const int* __restrict__ cnt, int* __restrict__ cur,
    int* __restrict__ srow, float* __restrict__ sval)
{
  const int e = blockIdx.x * 256 + threadIdx.x;
  if (e >= E) return;
  const int r = ei[e];
  const int c = ei[E + e];
  const int p = atomicAdd(&cur[c], 1);
  srow[p] = r;
  const int dr = cnt[r];
  const float dv = (float)dr * (float)cnt[c];
  sval[p] = (dr > 0) ? rsqrtf(dv) : 0.f;   // nan_to_num(inf)=0 when deg[row]==0
}

// ---------------- K6b: gather-accumulate agg[n] = sum val*hg[row] ----------------
__global__ __launch_bounds__(256) void k6b_gather(const int* __restrict__ ptr,
    const int* __restrict__ cnt, const int* __restrict__ srow,
    const float* __restrict__ sval, const float* __restrict__ hg,
    float* __restrict__ agg)
{
  const int t = threadIdx.x;
  const int n = blockIdx.x * 8 + (t >> 5);     // 8 nodes per block
  const int lane4 = (t & 31) * 4;
  const int start = ptr[n];
  const int end = start + cnt[n];
  float4 acc = make_float4(0.f, 0.f, 0.f, 0.f);
  int e = start;
  for (; e + 1 < end; e += 2) {
    int r0 = srow[e], r1 = srow[e + 1];
    float v0 = sval[e], v1 = sval[e + 1];
    float4 h0 = ld4(hg + (size_t)r0 * H + lane4);
    float4 h1 = ld4(hg + (size_t)r1 * H + lane4);
    acc.x += v0 * h0.x + v1 * h1.x;
    acc.y += v0 * h0.y + v1 * h1.y;
    acc.z += v0 * h0.z + v1 * h1.z;
    acc.w += v0 * h0.w + v1 * h1.w;
  }
  if (e < end) {
    int r0 = srow[e];
    float v0 = sval[e];
    float4 h0 = ld4(hg + (size_t)r0 * H + lane4);
    acc.x += v0 * h0.x;
    acc.y += v0 * h0.y;
    acc.z += v0 * h0.z;
    acc.w += v0 * h0.w;
  }
  st4(agg + (size_t)n * H + lane4, acc);
}

// ---------------- K7: conv GEMM + BN + relu + residual -> x2 (in-place in hg) ----------------
__global__ __launch_bounds__(256) void k7_conv(const float* __restrict__ agg,
    float* __restrict__ hg, const float* __restrict__ Wc,
    const float* __restrict__ cb, const float* __restrict__ g1,
    const float* __restrict__ b1)
{
  const int t = threadIdx.x;
  const int R0 = blockIdx.x * 32;
  const int r0 = (t >> 5) * 4;
  const int c0 = (t & 31) * 4;
  float acc[4][4] = {};
  for (int k0 = 0; k0 < H; k0 += 4) {
    float ax[4][4];
#pragma unroll
    for (int r = 0; r < 4; ++r) {
      float4 a4 = ld4(agg + (size_t)(R0 + r0 + r) * H + k0);
      ax[r][0] = a4.x; ax[r][1] = a4.y; ax[r][2] = a4.z; ax[r][3] = a4.w;
    }
#pragma unroll
    for (int kk = 0; kk < 4; ++kk) {
      float4 w = ld4(Wc + (size_t)(k0 + kk) * H + c0);
#pragma unroll
      for (int r = 0; r < 4; ++r) {
        float av = ax[r][kk];
        acc[r][0] += av * w.x; acc[r][1] += av * w.y;
        acc[r][2] += av * w.z; acc[r][3] += av * w.w;
      }
    }
  }
#pragma unroll
  for (int r = 0; r < 4; ++r) {
    size_t off = (size_t)(R0 + r0 + r) * H + c0;
    float4 res = ld4(hg + off);
    float rsv[4] = {res.x, res.y, res.z, res.w};
    float o[4];
#pragma unroll
    for (int j = 0; j < 4; ++j) {
      float v = (acc[r][j] + cb[c0 + j]) * IBN * g1[c0 + j] + b1[c0 + j];
      v = v > 0.f ? v : 0.f;
      o[j] = v + rsv[j];
    }
    st4(hg + off, make_float4(o[0], o[1], o[2], o[3]));
  }
}

// ---------------- K8: out = (0.8*x2 + 0.2*x1) @ fc_w + fc_b ----------------
__global__ __launch_bounds__(256) void k8_out(const float* __restrict__ ht,
    const float* __restrict__ hg, const float* __restrict__ W,
    const float* __restrict__ bias, float* __restrict__ out)
{
  const int t = threadIdx.x;
  const int R0 = blockIdx.x * 32;
  const int rr0 = (t >> 4) * 2;
  const int c0 = (t & 15) * 4;
  float acc[2][4] = {};
  for (int k0 = 0; k0 < H; k0 += 4) {
    float ax[2][4];
#pragma unroll
    for (int r = 0; r < 2; ++r) {
      size_t off = (size_t)(R0 + rr0 + r) * H + k0;
      float4 a1 = ld4(ht + off);
      float4 a2 = ld4(hg + off);
      ax[r][0] = 0.2f * a1.x + 0.8f * a2.x;
      ax[r][1] = 0.2f * a1.y + 0.8f * a2.y;
      ax[r][2] = 0.2f * a1.z + 0.8f * a2.z;
      ax[r][3] = 0.2f * a1.w + 0.8f * a2.w;
    }
#pragma unroll
    for (int kk = 0; kk < 4; ++kk) {
      float4 w = ld4(W + (size_t)(k0 + kk) * C + c0);
#pragma unroll
      for (int r = 0; r < 2; ++r) {
        float av = ax[r][kk];
        acc[r][0] += av * w.x; acc[r][1] += av * w.y;
        acc[r][2] += av * w.z; acc[r][3] += av * w.w;
      }
    }
  }
#pragma unroll
  for (int r = 0; r < 2; ++r) {
    float o[4];
#pragma unroll
    for (int j = 0; j < 4; ++j) o[j] = acc[r][j] + bias[c0 + j];
    st4(out + (size_t)(R0 + rr0 + r) * C + c0, make_float4(o[0], o[1], o[2], o[3]));
  }
}

// ---------------- launch ----------------
extern "C" void kernel_launch(void* const* d_in, const int* in_sizes, int n_in,
                              void* d_out, int out_size, void* d_ws, size_t ws_size,
                              hipStream_t stream) {
  (void)in_sizes; (void)n_in; (void)out_size; (void)ws_size;
  const float* x       = (const float*)d_in[0];
  const int*   ei      = (const int*)d_in[1];
  const float* t_fc_w  = (const float*)d_in[2];
  const float* t_fc_b  = (const float*)d_in[3];
  const float* t_ln0_g = (const float*)d_in[4];
  const float* t_ln0_b = (const float*)d_in[5];
  const float* t_wq_w  = (const float*)d_in[6];
  const float* t_wq_b  = (const float*)d_in[7];
  const float* t_wk_w  = (const float*)d_in[8];
  const float* t_wk_b  = (const float*)d_in[9];
  const float* t_wv_w  = (const float*)d_in[10];
  const float* t_wv_b  = (const float*)d_in[11];
  const float* t_ln1_g = (const float*)d_in[12];
  const float* t_ln1_b = (const float*)d_in[13];
  const float* g_fc_w  = (const float*)d_in[14];
  const float* g_fc_b  = (const float*)d_in[15];
  const float* g_bn0_g = (const float*)d_in[16];
  const float* g_bn0_b = (const float*)d_in[17];
  const float* g_cv_w  = (const float*)d_in[18];
  const float* g_cv_b  = (const float*)d_in[19];
  const float* g_bn1_g = (const float*)d_in[20];
  const float* g_bn1_b = (const float*)d_in[21];
  const float* fc_w    = (const float*)d_in[22];
  const float* fc_b    = (const float*)d_in[23];

  float* W    = (float*)d_ws;
  float* ht   = W + OFF_HT;
  float* hg   = W + OFF_HG;
  float* agg  = W + OFF_AGG;       // first: gram partials; then: gather output
  int*   cnt  = (int*)(W + OFF_CNT);
  float* s    = W + OFF_S;
  float* G    = W + OFF_G;
  int*   ptr  = (int*)(W + OFF_PTR);
  int*   cur  = (int*)(W + OFF_CUR);
  int*   bsum = (int*)(W + OFF_BS);
  int*   srow = (int*)(W + OFF_SROW);
  float* sval = W + OFF_SVAL;
  float* gw   = W + OFF_GWV;
  float* kv   = W + OFF_KV;
  float* ksum = W + OFF_KSUM;
  float* vsum = W + OFF_VSUM;
  float* qsum = W + OFF_QSUM;
  float* sc   = W + OFF_SC;
  unsigned short* Bt2 = (unsigned short*)(W + OFF_B);
  float* cc   = W + OFF_CC;
  float* u    = W + OFF_U;
  float* u0   = W + OFF_U0;
  unsigned short* Bt = (unsigned short*)(W + OFF_BT);

  hipMemsetAsync(cnt, 0, N * sizeof(int), stream);

  // weight pack for MFMA k1 (gload_lds tile-order layout)
  k0_cvt<<<512, 256, 0, stream>>>(t_fc_w, g_fc_w, Bt);

  // graph branch CSR build (independent of k1)
  k5_deg<<<(E + 255) / 256, 256, 0, stream>>>(ei, cnt);
  k_scan1<<<NB1024, 256, 0, stream>>>(cnt, bsum);
  k_scan2<<<1, 64, 0, stream>>>(bsum);
  k_scan3<<<NB1024, 256, 0, stream>>>(cnt, bsum, ptr, cur);
  k6a_place<<<E / 256, 256, 0, stream>>>(ei, cnt, cur, srow, sval);

  k1_mfma<<<(N + 63) / 64, 256, 0, stream>>>(x, Bt, t_fc_b, t_ln0_g, t_ln0_b,
                                             g_fc_b, g_bn0_g, g_bn0_b, ht, hg);
  // trans reductions FIRST (partials live in agg, freed before gather overwrites)
  k2_gram<<<NB_GRAM, 256, 0, stream>>>(ht, agg, agg + SP_BASE);
  k2r_reduce<<<64, 256, 0, stream>>>(agg, agg + SP_BASE, G, s);
  // graph aggregation (gather) — overwrites agg
  k6b_gather<<<N / 8, 256, 0, stream>>>(ptr, cnt, srow, sval, hg, agg);
  k3a_gw<<<384, 256, 0, stream>>>(G, t_wv_w, t_wk_w, t_wq_w, gw);
  k3k_sums<<<3, 256, 0, stream>>>(s, t_wk_w, t_wk_b, t_wv_w, t_wv_b, t_wq_w, t_wq_b,
                                  ksum, vsum, qsum);
  k3b_kv<<<128, 256, 0, stream>>>(gw, s, t_wk_w, t_wk_b, t_wv_b, vsum, kv);
  k3c_ssq<<<1, 256, 0, stream>>>(t_wk_w, gw + 32768, t_wq_w, gw + 65536,
                                 t_wk_b, ksum, t_wq_b, qsum, sc);
  k3d_B<<<128, 256, 0, stream>>>(t_wq_w, kv, t_wv_w, sc, Bt2);
  k3e_small<<<1, 512, 0, stream>>>(t_wq_b, kv, t_wv_b, t_wq_w, ksum, sc, cc, u, u0);
  k4_mfma<<<(N + 63) / 64, 256, 0, stream>>>(ht, Bt2, cc, u, u0, t_ln1_g, t_ln1_b);
  // graph tail + output
  k7_conv<<<N / 32, 256, 0, stream>>>(agg, hg, g_cv_w, g_cv_b, g_bn1_g, g_bn1_b);
  k8_out<<<N / 32, 256, 0, stream>>>(ht, hg, fc_w, fc_b, (float*)d_out);
}

// Round 5
// 1144.920 us; speedup vs baseline: 1.0469x; 1.0469x over previous
//
#include <hip/hip_runtime.h>

// ---------------- problem constants ----------------
constexpr int N = 100000;
constexpr int F = 512;
constexpr int H = 128;
constexpr int E = 1600000;
constexpr int C = 64;
constexpr float EPS = 1e-5f;
constexpr float NF = 100000.0f;     // number of nodes as float
constexpr float IBN = 0.999995000037f; // 1/sqrt(1+1e-5)

// ---------------- workspace layout (float offsets) ----------------
constexpr size_t OFF_HT   = 0;                     // [N,H] trans hidden, later x1 (in-place)
constexpr size_t OFF_HG   = 12800000;              // [N,H] graph hidden, later x2 (in-place)
constexpr size_t OFF_AGG  = 25600000;              // [N,H]; FIRST reused as gram partials, THEN gather output
constexpr size_t OFF_CNT  = 38400000;              // int[N] in-degree  (zeroed)
constexpr size_t OFF_S    = 38500000;              // [128] colsum (written by k2r)
constexpr size_t OFF_G    = 38500128;              // [128,128] gram (written by k2r)
constexpr size_t OFF_PTR  = 38516512;              // int[N] CSR bucket starts
constexpr size_t OFF_CUR  = 38616512;              // int[N] placement cursors
constexpr size_t OFF_BS   = 38716512;              // int[128] scan block offsets
constexpr size_t OFF_SROW = 38716640;              // int[E] sorted src rows
constexpr size_t OFF_SVAL = 40316640;              // float[E] sorted edge weights
constexpr size_t OFF_GWV  = 41916640;              // 3 x [128,256]: G@Wv, G@Wk, G@Wq
constexpr size_t OFF_KV   = OFF_GWV + 3 * 32768;   // [2,128,128] kv_raw
constexpr size_t OFF_KSUM = OFF_KV + 32768;        // [256]
constexpr size_t OFF_VSUM = OFF_KSUM + 256;        // [256]
constexpr size_t OFF_QSUM = OFF_VSUM + 256;        // [256]
constexpr size_t OFF_SC   = OFF_QSUM + 256;        // [4]
constexpr size_t OFF_B    = OFF_SC + 4;            // bf16 Bt2[256][128] (16384 floats used of 32768)
constexpr size_t OFF_CC   = OFF_B + 32768;         // [256]
constexpr size_t OFF_U    = OFF_CC + 256;          // [128,2]
constexpr size_t OFF_U0   = OFF_U + 256;           // [2] (+2 pad)
constexpr size_t OFF_BT   = OFF_U0 + 4;            // bf16[16 kt][1024 chunks][8] = 65536 floats

constexpr int NB1024 = (N + 1023) / 1024;          // 98 scan blocks
constexpr int NB_GRAM = (N + 255) / 256;           // 391 gram blocks
constexpr size_t SP_BASE = (size_t)NB_GRAM * 16384; // colsum partials offset inside agg

typedef __attribute__((ext_vector_type(8))) short short8;
typedef __attribute__((ext_vector_type(4))) float floatx4;

__device__ __forceinline__ float4 ld4(const float* p) {
  return *reinterpret_cast<const float4*>(p);
}
__device__ __forceinline__ void st4(float* p, float4 v) {
  *reinterpret_cast<float4*>(p) = v;
}
__device__ __forceinline__ unsigned short f2bf(float f) {
  unsigned u = __float_as_uint(f);
  u += 0x7fff + ((u >> 16) & 1);       // RNE
  return (unsigned short)(u >> 16);
}
__device__ __forceinline__ float bf2f(unsigned short h) {
  return __uint_as_float((unsigned)h << 16);
}
// async global->LDS 16B copy (per-lane global addr, wave-uniform LDS base; HW adds lane*16)
__device__ __forceinline__ void gl_lds16(const unsigned short* g, unsigned short* l) {
  __builtin_amdgcn_global_load_lds(
      (const __attribute__((address_space(1))) unsigned int*)g,
      (__attribute__((address_space(3))) unsigned int*)l, 16, 0, 0);
}

// ---------------- K0: pack Wt||Wg -> bf16 Bt in gload_lds tile order ----------------
// Per K-step kt (32 wide), tile = 1024 chunks of 16B (8 bf16).
// Logical chunk for (k,n): g=(k>>3)&3, chunk = g*256 + ((n + 2g) & 255), element e = k&7.
__global__ __launch_bounds__(256) void k0_cvt(const float* __restrict__ Wt,
    const float* __restrict__ Wg, unsigned short* __restrict__ Bt)
{
  const int idx = blockIdx.x * 256 + threadIdx.x;   // < 131072
  const int k = idx >> 8;       // 0..511
  const int n = idx & 255;      // 0..255
  float v = (n < 128) ? Wt[(size_t)k * H + n] : Wg[(size_t)k * H + (n - 128)];
  const int kt = k >> 5;            // 0..15
  const int g  = (k >> 3) & 3;      // 0..3
  const int e  = k & 7;
  const int chunk = g * 256 + ((n + 2 * g) & 255);
  Bt[(((size_t)kt * 1024 + chunk) << 3) + e] = f2bf(v);
}

// ---------------- K1: MFMA fused fc GEMMs, 512-thread 2-phase dbuf pipeline ----------------
// 128 rows/block, 8 waves (4x2 wave grid over 128x256 output), BK=32, 16 K-steps.
// Same per-wave structure as the proven 141us version, but 2x rows/block so the
// 53KB LDS serves 8 waves: occupancy becomes VGPR-capped at 16 waves/CU (vs 12).
// Epilogue is fully in-register (shfl LN) so no 34KB ln staging union is needed.
__global__ __launch_bounds__(512, 4) void k1_mfma(
    const float* __restrict__ x, const unsigned short* __restrict__ Bt,
    const float* __restrict__ bt, const float* __restrict__ lng, const float* __restrict__ lnb,
    const float* __restrict__ bgv, const float* __restrict__ bng, const float* __restrict__ bnb,
    float* __restrict__ ht, float* __restrict__ hg)
{
  __shared__ __align__(16) struct {
    unsigned short A[2][128 * 40];   // 20480 B (32 data + 8 pad shorts per row)
    unsigned short B[2][8192];       // 32768 B (1024 chunks of 16B per buffer)
  } sm;                              // 53248 B total
  const int t = threadIdx.x;        // 0..511
  const int lane = t & 63;
  const int w = t >> 6;             // 0..7
  const int rq = (w >> 1) * 32;     // wave row base: 0/32/64/96
  const int cq = (w & 1) * 128;     // wave col base: 0/128
  const int g = lane >> 4;          // 0..3
  const int m = lane & 15;
  const int M0 = blockIdx.x * 128;

  floatx4 acc[2][8];
#pragma unroll
  for (int rt = 0; rt < 2; ++rt)
#pragma unroll
    for (int ct = 0; ct < 8; ++ct) acc[rt][ct] = (floatx4){0.f, 0.f, 0.f, 0.f};

  // A staging: thread t covers row t>>2 (0..127), 8 cols at (t&3)*8 within the 32-wide K slice
  const int srow = t >> 2;
  const int scol8 = (t & 3) * 8;
  const int grow = (M0 + srow < N) ? (M0 + srow) : (N - 1);
  const float* xp = x + (size_t)grow * F + scol8;

  // B fragment chunk base (g-rotated)
  const int mb = cq + m + 2 * g;    // + ct*16, & 255 at use
  const int ldsw = (w << 6);        // wave's 64-chunk segment base

  // ---- prologue: stage kt=0 into buf 0 ----
  {
#pragma unroll
    for (int i = 0; i < 2; ++i)
      gl_lds16(Bt + (((size_t)(i * 512 + t)) << 3),
               &sm.B[0][(size_t)(i * 512 + ldsw) << 3]);
    float4 a0 = ld4(xp), a1 = ld4(xp + 4);
    ushort4 p0, p1;
    p0.x = f2bf(a0.x); p0.y = f2bf(a0.y); p0.z = f2bf(a0.z); p0.w = f2bf(a0.w);
    p1.x = f2bf(a1.x); p1.y = f2bf(a1.y); p1.z = f2bf(a1.z); p1.w = f2bf(a1.w);
    *(ushort4*)(sm.A[0] + srow * 40 + scol8) = p0;
    *(ushort4*)(sm.A[0] + srow * 40 + scol8 + 4) = p1;
  }
  __syncthreads();   // drains vmcnt (incl. gload_lds) + lgkmcnt

#pragma unroll 2
  for (int kt = 0; kt < 16; ++kt) {
    const int cur = kt & 1, nxt = cur ^ 1;
    float4 a0, a1;
    const bool more = (kt + 1 < 16);
    if (more) {
      // issue next B tile (async to LDS) and next A slice (to regs)
#pragma unroll
      for (int i = 0; i < 2; ++i)
        gl_lds16(Bt + (((size_t)(kt + 1) * 1024 + i * 512 + t) << 3),
                 &sm.B[nxt][(size_t)(i * 512 + ldsw) << 3]);
      a0 = ld4(xp + (kt + 1) * 32);
      a1 = ld4(xp + (kt + 1) * 32 + 4);
    }
    // compute current tile
    {
      const unsigned short* Ab = sm.A[cur];
      const unsigned short* Bb = sm.B[cur];
      short8 af[2], bf[8];
#pragma unroll
      for (int rt = 0; rt < 2; ++rt)
        af[rt] = *(const short8*)(Ab + (rq + rt * 16 + m) * 40 + g * 8);
#pragma unroll
      for (int ct = 0; ct < 8; ++ct) {
        const int chunk = g * 256 + ((mb + ct * 16) & 255);
        bf[ct] = *(const short8*)(Bb + ((size_t)chunk << 3));
      }
#pragma unroll
      for (int rt = 0; rt < 2; ++rt)
#pragma unroll
        for (int ct = 0; ct < 8; ++ct)
          acc[rt][ct] = __builtin_amdgcn_mfma_f32_16x16x32_bf16(af[rt], bf[ct], acc[rt][ct], 0, 0, 0);
    }
    if (more) {
      ushort4 p0, p1;
      p0.x = f2bf(a0.x); p0.y = f2bf(a0.y); p0.z = f2bf(a0.z); p0.w = f2bf(a0.w);
      p1.x = f2bf(a1.x); p1.y = f2bf(a1.y); p1.z = f2bf(a1.z); p1.w = f2bf(a1.w);
      *(ushort4*)(sm.A[nxt] + srow * 40 + scol8) = p0;
      *(ushort4*)(sm.A[nxt] + srow * 40 + scol8 + 4) = p1;
    }
    __syncthreads();   // single drain per K-step: buf[nxt] complete, buf[cur] free
  }

  // ---- epilogue, fully in-register. C/D layout: col = ct*16+m, row = rt*16+g*4+r ----
  if (cq == 0) {
    // ht half: bias + LN + relu; wave holds the FULL 128-col row -> shfl reduce
    float bt_l[8], lng_l[8], lnb_l[8];
#pragma unroll
    for (int ct = 0; ct < 8; ++ct) {
      bt_l[ct] = bt[ct * 16 + m];
      lng_l[ct] = lng[ct * 16 + m];
      lnb_l[ct] = lnb[ct * 16 + m];
    }
#pragma unroll
    for (int rt = 0; rt < 2; ++rt) {
#pragma unroll
      for (int r = 0; r < 4; ++r) {
        float sum = 0.f, sq = 0.f;
#pragma unroll
        for (int ct = 0; ct < 8; ++ct) {
          float v = acc[rt][ct][r] + bt_l[ct];
          acc[rt][ct][r] = v;
          sum += v; sq += v * v;
        }
        // reduce across the 16-lane m-group (masks 1,2,4,8 stay within group)
#pragma unroll
        for (int off = 1; off < 16; off <<= 1) {
          sum += __shfl_xor(sum, off, 64);
          sq  += __shfl_xor(sq,  off, 64);
        }
        const float mu = sum * (1.f / H);
        const float rs = rsqrtf(sq * (1.f / H) - mu * mu + EPS);
        const int row = M0 + rq + rt * 16 + g * 4 + r;
        if (row < N) {
          float* hp = ht + (size_t)row * H + m;
#pragma unroll
          for (int ct = 0; ct < 8; ++ct) {
            float o = (acc[rt][ct][r] - mu) * rs * lng_l[ct] + lnb_l[ct];
            hp[ct * 16] = o > 0.f ? o : 0.f;
          }
        }
      }
    }
  } else {
    // hg half: bias + BN + relu, elementwise
#pragma unroll
    for (int ct = 0; ct < 8; ++ct) {
      const int c2 = ct * 16 + m;
      const float s1 = IBN * bng[c2], b0 = bgv[c2], b2v = bnb[c2];
#pragma unroll
      for (int rt = 0; rt < 2; ++rt) {
#pragma unroll
        for (int r = 0; r < 4; ++r) {
          const int row = M0 + rq + rt * 16 + g * 4 + r;
          if (row < N) {
            float v = (acc[rt][ct][r] + b0) * s1 + b2v;
            hg[(size_t)row * H + c2] = v > 0.f ? v : 0.f;
          }
        }
      }
    }
  }
}

// ---------------- K2: gram + colsum partials, NO atomics ----------------
__global__ __launch_bounds__(256) void k2_gram(const float* __restrict__ ht,
                                               float* __restrict__ gp,   // [NB_GRAM][16384]
                                               float* __restrict__ sp)   // [NB_GRAM][128]
{
  const int t = threadIdx.x;
  const int b = blockIdx.x;
  const int base = b * 256;
  const int nend = (base + 256 < N) ? base + 256 : N;
  const int r0 = (t >> 4) * 8;
  const int c0 = (t & 15) * 8;
  float acc[8][8] = {};
  float colacc[8] = {};
  const bool do_col = (t < 16);
  int n = base;
  for (; n + 1 < nend; n += 2) {
    const float* hp0 = ht + (size_t)n * H;
    const float* hp1 = hp0 + H;
    float4 a00 = ld4(hp0 + r0), a01 = ld4(hp0 + r0 + 4);
    float4 b00 = ld4(hp0 + c0), b01 = ld4(hp0 + c0 + 4);
    float4 a10 = ld4(hp1 + r0), a11 = ld4(hp1 + r0 + 4);
    float4 b10 = ld4(hp1 + c0), b11 = ld4(hp1 + c0 + 4);
    float a0[8] = {a00.x, a00.y, a00.z, a00.w, a01.x, a01.y, a01.z, a01.w};
    float b0[8] = {b00.x, b00.y, b00.z, b00.w, b01.x, b01.y, b01.z, b01.w};
    float a1[8] = {a10.x, a10.y, a10.z, a10.w, a11.x, a11.y, a11.z, a11.w};
    float b1[8] = {b10.x, b10.y, b10.z, b10.w, b11.x, b11.y, b11.z, b11.w};
    if (do_col) {
#pragma unroll
      for (int j = 0; j < 8; ++j) colacc[j] += b0[j] + b1[j];
    }
#pragma unroll
    for (int i = 0; i < 8; ++i)
#pragma unroll
      for (int j = 0; j < 8; ++j)
        acc[i][j] += a0[i] * b0[j] + a1[i] * b1[j];
  }
  if (n < nend) {
    const float* hp0 = ht + (size_t)n * H;
    float4 a00 = ld4(hp0 + r0), a01 = ld4(hp0 + r0 + 4);
    float4 b00 = ld4(hp0 + c0), b01 = ld4(hp0 + c0 + 4);
    float a0[8] = {a00.x, a00.y, a00.z, a00.w, a01.x, a01.y, a01.z, a01.w};
    float b0[8] = {b00.x, b00.y, b00.z, b00.w, b01.x, b01.y, b01.z, b01.w};
    if (do_col) {
#pragma unroll
      for (int j = 0; j < 8; ++j) colacc[j] += b0[j];
    }
#pragma unroll
    for (int i = 0; i < 8; ++i)
#pragma unroll
      for (int j = 0; j < 8; ++j)
        acc[i][j] += a0[i] * b0[j];
  }
  float* g = gp + (size_t)b * 16384;
#pragma unroll
  for (int i = 0; i < 8; ++i) {
    st4(&g[(r0 + i) * H + c0], make_float4(acc[i][0], acc[i][1], acc[i][2], acc[i][3]));
    st4(&g[(r0 + i) * H + c0 + 4], make_float4(acc[i][4], acc[i][5], acc[i][6], acc[i][7]));
  }
  if (do_col) {
    float* spb = sp + (size_t)b * 128;
    st4(&spb[c0], make_float4(colacc[0], colacc[1], colacc[2], colacc[3]));
    st4(&spb[c0 + 4], make_float4(colacc[4], colacc[5], colacc[6], colacc[7]));
  }
}

// ---------------- K2r: reduce partials -> G, s ----------------
__global__ __launch_bounds__(256) void k2r_reduce(const float* __restrict__ gp,
    const float* __restrict__ sp, float* __restrict__ G, float* __restrict__ s)
{
  const int i = blockIdx.x * 256 + threadIdx.x;   // < 16384
  float s0 = 0.f, s1 = 0.f, s2 = 0.f, s3 = 0.f;
  int b = 0;
  for (; b + 3 < NB_GRAM; b += 4) {
    s0 += gp[(size_t)b * 16384 + i];
    s1 += gp[(size_t)(b + 1) * 16384 + i];
    s2 += gp[(size_t)(b + 2) * 16384 + i];
    s3 += gp[(size_t)(b + 3) * 16384 + i];
  }
  for (; b < NB_GRAM; ++b) s0 += gp[(size_t)b * 16384 + i];
  G[i] = (s0 + s1) + (s2 + s3);
  if (blockIdx.x == 0 && threadIdx.x < 128) {
    float t0 = 0.f, t1 = 0.f;
    int bb = 0;
    for (; bb + 1 < NB_GRAM; bb += 2) {
      t0 += sp[(size_t)bb * 128 + threadIdx.x];
      t1 += sp[(size_t)(bb + 1) * 128 + threadIdx.x];
    }
    for (; bb < NB_GRAM; ++bb) t0 += sp[(size_t)bb * 128 + threadIdx.x];
    s[threadIdx.x] = t0 + t1;
  }
}

// ---------------- K3a: GW = G @ {Wv, Wk, Wq} ----------------
__global__ __launch_bounds__(256) void k3a_gw(const float* __restrict__ G,
    const float* __restrict__ Wv, const float* __restrict__ Wk,
    const float* __restrict__ Wq, float* __restrict__ GW)
{
  const int flat = blockIdx.x * 256 + threadIdx.x;   // < 98304
  const int w = flat >> 15;
  const int rem = flat & 32767;
  const int i = rem >> 8;
  const int j = rem & 255;
  const float* W = (w == 0) ? Wv : (w == 1) ? Wk : Wq;
  float sum = 0.f;
#pragma unroll 8
  for (int k = 0; k < H; ++k) sum += G[i * H + k] * W[k * 256 + j];
  GW[flat] = sum;
}

// ---------------- K3k: ksum/vsum/qsum = s @ W + N*b ----------------
__global__ __launch_bounds__(256) void k3k_sums(const float* __restrict__ s,
    const float* __restrict__ Wk, const float* __restrict__ bk,
    const float* __restrict__ Wv, const float* __restrict__ bv,
    const float* __restrict__ Wq, const float* __restrict__ bq,
    float* __restrict__ ksum, float* __restrict__ vsum, float* __restrict__ qsum)
{
  const int flat = blockIdx.x * 256 + threadIdx.x;   // < 768
  const int w = flat >> 8;
  const int j = flat & 255;
  const float* W = (w == 0) ? Wk : (w == 1) ? Wv : Wq;
  const float* b = (w == 0) ? bk : (w == 1) ? bv : bq;
  float* out = (w == 0) ? ksum : (w == 1) ? vsum : qsum;
  float sum = 0.f;
#pragma unroll 8
  for (int k = 0; k < H; ++k) sum += s[k] * W[k * 256 + j];
  out[j] = sum + NF * b[j];
}

// ---------------- K3b: kv_raw[h,m,d] ----------------
__global__ __launch_bounds__(256) void k3b_kv(const float* __restrict__ GWv,
    const float* __restrict__ s, const float* __restrict__ Wk,
    const float* __restrict__ bk, const float* __restrict__ bv,
    const float* __restrict__ vsum, float* __restrict__ kv)
{
  const int flat = blockIdx.x * 256 + threadIdx.x;   // < 32768
  const int h = flat >> 14;
  const int m = (flat >> 7) & 127;
  const int d = flat & 127;
  float s1 = 0.f, s2 = 0.f;
#pragma unroll 4
  for (int k = 0; k < H; ++k) {
    float wkv = Wk[k * 256 + h * 128 + m];
    s1 += wkv * GWv[k * 256 + h * 128 + d];
    s2 += wkv * s[k];
  }
  kv[flat] = s1 + s2 * bv[h * 128 + d] + bk[h * 128 + m] * vsum[h * 128 + d];
}

// ---------------- K3c: ssq_q, ssq_k, inv ----------------
__global__ __launch_bounds__(256) void k3c_ssq(
    const float* __restrict__ Wk, const float* __restrict__ GWk,
    const float* __restrict__ Wq, const float* __restrict__ GWq,
    const float* __restrict__ bk, const float* __restrict__ ksum,
    const float* __restrict__ bq, const float* __restrict__ qsum,
    float* __restrict__ sc)
{
  __shared__ float red[512];
  const int t = threadIdx.x;
  float pk = 0.f, pq = 0.f;
  for (int i = t; i < 32768; i += 256) {
    pk += Wk[i] * GWk[i];
    pq += Wq[i] * GWq[i];
  }
  pk += 2.f * bk[t] * ksum[t] - NF * bk[t] * bk[t];
  pq += 2.f * bq[t] * qsum[t] - NF * bq[t] * bq[t];
  red[t] = pk; red[256 + t] = pq;
  __syncthreads();
  for (int off = 128; off > 0; off >>= 1) {
    if (t < off) { red[t] += red[t + off]; red[256 + t] += red[256 + t + off]; }
    __syncthreads();
  }
  if (t == 0) {
    float ssq_k = red[0], ssq_q = red[256];
    sc[0] = ssq_q; sc[1] = ssq_k;
    sc[2] = rsqrtf(ssq_q * ssq_k);   // 1/(||q|| * ||k||)
  }
}

// ---------------- K3d: B = Wq @ kv * inv + N*Wv -> packed bf16 Bt2[n=256][k=128] ----------------
__global__ __launch_bounds__(256) void k3d_B(const float* __restrict__ Wq,
    const float* __restrict__ kv, const float* __restrict__ Wv,
    const float* __restrict__ sc, unsigned short* __restrict__ Bt2)
{
  const int flat = blockIdx.x * 256 + threadIdx.x;   // < 32768
  const int i = flat >> 8;       // 0..127 : k-dim (h index)
  const int j = flat & 255;      // 0..255 : col (head*128 + d)
  const int h = j >> 7;
  const int d = j & 127;
  const float inv = sc[2];
  float sum = 0.f;
#pragma unroll 4
  for (int m = 0; m < H; ++m)
    sum += Wq[i * 256 + h * 128 + m] * kv[h * 16384 + m * 128 + d];
  Bt2[(size_t)j * H + i] = f2bf(sum * inv + NF * Wv[i * 256 + j]);
}

// ---------------- K3e: c, u, u0 ----------------
__global__ __launch_bounds__(512) void k3e_small(const float* __restrict__ bq,
    const float* __restrict__ kv, const float* __restrict__ bv,
    const float* __restrict__ Wq, const float* __restrict__ ksum,
    const float* __restrict__ sc, float* __restrict__ cc,
    float* __restrict__ u, float* __restrict__ u0)
{
  const int t = threadIdx.x;
  const float inv = sc[2];
  if (t < 256) {
    const int h = t >> 7, d = t & 127;
    float sum = 0.f;
    for (int m = 0; m < H; ++m) sum += bq[h * 128 + m] * kv[h * 16384 + m * 128 + d];
    cc[t] = sum * inv + NF * bv[t];
  } else {
    const int q = t - 256;
    const int i = q >> 1, h = q & 1;
    float sum = 0.f;
    for (int m = 0; m < H; ++m) sum += Wq[i * 256 + h * 128 + m] * ksum[h * 128 + m];
    u[i * 2 + h] = sum * inv;
  }
  if (t < 2) {
    float sum = 0.f;
    for (int m = 0; m < H; ++m) sum += bq[t * 128 + m] * ksum[t * 128 + m];
    u0[t] = sum * inv + NF;
  }
}

// ---------------- K4: MFMA attention apply + residual + LN -> x1 (in-place in ht) ----------------
// 64-row tile; 4 waves; each wave: 16 rows x all 256 cols (head combine is in-lane: ct vs ct+8)
__global__ __launch_bounds__(256) void k4_mfma(float* __restrict__ ht,
    const unsigned short* __restrict__ Bt2, const float* __restrict__ cc,
    const float* __restrict__ u, const float* __restrict__ u0,
    const float* __restrict__ lng, const float* __restrict__ lnb)
{
  __shared__ __align__(16) union {
    unsigned short A[64 * 136];       // 17408 B (bf16 ht tile)
    float lns[64 * 132];              // 33792 B (LN staging)
  } sm;
  __shared__ float u_s[256];
  __shared__ float rden_s[128];       // [row][head]
  __shared__ float mu_s[64], rs_s[64];
  const int t = threadIdx.x;
  const int lane = t & 63;
  const int w = t >> 6;
  const int rq = w * 16;              // wave row base 0/16/32/48
  const int g = lane >> 4;
  const int m = lane & 15;
  const int M0 = blockIdx.x * 64;

  // stage A: ht rows fp32 -> bf16 LDS (K=128 fits entirely)
  {
    const int srow = t >> 2;          // 0..63
    const int scol = (t & 3) * 32;    // 0,32,64,96
    const int grow = (M0 + srow < N) ? (M0 + srow) : (N - 1);
    const float* xp = ht + (size_t)grow * H + scol;
#pragma unroll
    for (int j = 0; j < 8; ++j) {
      float4 a4 = ld4(xp + j * 4);
      ushort4 p;
      p.x = f2bf(a4.x); p.y = f2bf(a4.y); p.z = f2bf(a4.z); p.w = f2bf(a4.w);
      *(ushort4*)(sm.A + srow * 136 + scol + j * 4) = p;
    }
  }
  u_s[t] = u[t];
  __syncthreads();

  floatx4 acc[16];
#pragma unroll
  for (int ct = 0; ct < 16; ++ct) acc[ct] = (floatx4){0.f, 0.f, 0.f, 0.f};
#pragma unroll
  for (int kk = 0; kk < 128; kk += 32) {
    short8 af = *(const short8*)(sm.A + (rq + m) * 136 + kk + g * 8);
#pragma unroll
    for (int ct = 0; ct < 16; ++ct) {
      short8 bf = *(const short8*)(Bt2 + (size_t)(ct * 16 + m) * H + kk + g * 8);
      acc[ct] = __builtin_amdgcn_mfma_f32_16x16x32_bf16(af, bf, acc[ct], 0, 0, 0);
    }
  }
  // denominators (waves 0,1): row=t>>1, head=t&1
  if (t < 128) {
    const int row = t >> 1, head = t & 1;
    float den = u0[head];
    for (int k = 0; k < H; ++k)
      den += bf2f(sm.A[row * 136 + k]) * u_s[k * 2 + head];
    rden_s[row * 2 + head] = 0.5f / den;   // mean-over-heads folded
  }
  __syncthreads();   // A fully consumed; lns may now overwrite the union

  // combine heads + residual -> lns
#pragma unroll
  for (int ct = 0; ct < 8; ++ct) {
    const int d = ct * 16 + m;
    const float c0v = cc[d], c1v = cc[128 + d];
#pragma unroll
    for (int r = 0; r < 4; ++r) {
      const int row = rq + g * 4 + r;         // block-local 0..63
      const int grow = M0 + row;
      const float rd0 = rden_s[row * 2], rd1 = rden_s[row * 2 + 1];
      float attn = (acc[ct][r] + c0v) * rd0 + (acc[ct + 8][r] + c1v) * rd1;
      float hres = (grow < N) ? ht[(size_t)grow * H + d] : 0.f;
      sm.lns[row * 132 + d] = (attn + hres) * 0.5f;
    }
  }
  __syncthreads();
  if (t < 64) {
    float sum = 0.f, sq = 0.f;
    for (int c2 = 0; c2 < H; ++c2) {
      float v = sm.lns[t * 132 + c2];
      sum += v; sq += v * v;
    }
    float mu = sum * (1.f / H);
    float var = sq * (1.f / H) - mu * mu;
    mu_s[t] = mu; rs_s[t] = rsqrtf(var + EPS);
  }
  __syncthreads();
  {
    const int r = t >> 2;
    const int cb = (t & 3) * 32;
    if (M0 + r < N) {
      const float mu = mu_s[r], rs = rs_s[r];
#pragma unroll
      for (int j = 0; j < 8; ++j) {
        const int c = cb + j * 4;
        float o[4];
#pragma unroll
        for (int q = 0; q < 4; ++q) {
          float v = (sm.lns[r * 132 + c + q] - mu) * rs * lng[c + q] + lnb[c + q];
          o[q] = v > 0.f ? v : 0.f;
        }
        st4(ht + (size_t)(M0 + r) * H + c, make_float4(o[0], o[1], o[2], o[3]));
      }
    }
  }
}

// ---------------- K5: in-degree (int counts) ----------------
__global__ __launch_bounds__(256) void k5_deg(const int* __restrict__ ei,
                                              int* __restrict__ cnt)
{
  const int i = blockIdx.x * 256 + threadIdx.x;
  if (i < E) atomicAdd(&cnt[ei[E + i]], 1);
}

// ---------------- scan1: per-1024-chunk sums ----------------
__global__ __launch_bounds__(256) void k_scan1(const int* __restrict__ cnt,
                                               int* __restrict__ bsum)
{
  __shared__ int red[256];
  const int t = threadIdx.x;
  const int base = blockIdx.x * 1024 + t * 4;
  int s = 0;
#pragma unroll
  for (int j = 0; j < 4; ++j) {
    int idx = base + j;
    if (idx < N) s += cnt[idx];
  }
  red[t] = s;
  __syncthreads();
  for (int off = 128; off > 0; off >>= 1) {
    if (t < off) red[t] += red[t + off];
    __syncthreads();
  }
  if (t == 0) bsum[blockIdx.x] = red[0];
}

// ---------------- scan2: parallel exclusive scan of 98 block sums ----------------
__global__ __launch_bounds__(128) void k_scan2(int* __restrict__ bsum)
{
  __shared__ int sh[128];
  const int t = threadIdx.x;
  const int v = (t < NB1024) ? bsum[t] : 0;
  sh[t] = v;
  __syncthreads();
  for (int off = 1; off < 128; off <<= 1) {
    int add = (t >= off) ? sh[t - off] : 0;
    __syncthreads();
    sh[t] += add;
    __syncthreads();
  }
  if (t < NB1024) bsum[t] = sh[t] - v;   // exclusive
}

// ---------------- scan3: intra-chunk exclusive scan -> ptr, cur ----------------
__global__ __launch_bounds__(256) void k_scan3(const int* __restrict__ cnt,
    const int* __restrict__ bsum, int* __restrict__ ptr, int* __restrict__ cur)
{
  __shared__ int part[256];
  const int t = threadIdx.x;
  const int base = blockIdx.x * 1024 + t * 4;
  int v[4];
  int tsum = 0;
#pragma unroll
  for (int j = 0; j < 4; ++j) {
    int idx = base + j;
    v[j] = (idx < N) ? cnt[idx] : 0;
    tsum += v[j];
  }
  part[t] = tsum;
  __syncthreads();
  for (int off = 1; off < 256; off <<= 1) {
    int add = (t >= off) ? part[t - off] : 0;
    __syncthreads();
    part[t] += add;
    __syncthreads();
  }
  int run = bsum[blockIdx.x] + part[t] - tsum;
#pragma unroll
  for (int j = 0; j < 4; ++j) {
    int idx = base + j;
    if (idx < N) { ptr[idx] = run; cur[idx] = run; }
    run += v[j];
  }
}

// ---------------- K6a: place edges into destination buckets ----------------
__global__ __launch_bounds__(256) void k6a_place(const int* __restrict__ ei,
    const int* __restrict__ cnt, int* __restrict__ cur,
    int* __restrict__ srow, float* __restrict__ sval)
{
  const int e = blockIdx.x * 256 + threadIdx.x;
  if (e >= E) return;
  const int r = ei[e];
  const int c = ei[E + e];
  const int p = atomicAdd(&cur[c], 1);
  srow[p] = r;
  const int dr = cnt[r];
  const float dv = (float)dr * (float)cnt[c];
  sval[p] = (dr > 0) ? rsqrtf(dv) : 0.f;   // nan_to_num(inf)=0 when deg[row]==0
}

// ---------------- K6b: gather-accumulate agg[n] = sum val*hg[row] ----------------
__global__ __launch_bounds__(256) void k6b_gather(const int* __restrict__ ptr,
    const int* __restrict__ cnt, const int* __restrict__ srow,
    const float* __restrict__ sval, const float* __restrict__ hg,
    float* __restrict__ agg)
{
  const int t = threadIdx.x;
  const int n = blockIdx.x * 8 + (t >> 5);     // 8 nodes per block
  const int lane4 = (t & 31) * 4;
  const int start = ptr[n];
  const int end = start + cnt[n];
  float4 acc = make_float4(0.f, 0.f, 0.f, 0.f);
  int e = start;
  for (; e + 1 < end; e += 2) {
    int r0 = srow[e], r1 = srow[e + 1];
    float v0 = sval[e], v1 = sval[e + 1];
    float4 h0 = ld4(hg + (size_t)r0 * H + lane4);
    float4 h1 = ld4(hg + (size_t)r1 * H + lane4);
    acc.x += v0 * h0.x + v1 * h1.x;
    acc.y += v0 * h0.y + v1 * h1.y;
    acc.z += v0 * h0.z + v1 * h1.z;
    acc.w += v0 * h0.w + v1 * h1.w;
  }
  if (e < end) {
    int r0 = srow[e];
    float v0 = sval[e];
    float4 h0 = ld4(hg + (size_t)r0 * H + lane4);
    acc.x += v0 * h0.x;
    acc.y += v0 * h0.y;
    acc.z += v0 * h0.z;
    acc.w += v0 * h0.w;
  }
  st4(agg + (size_t)n * H + lane4, acc);
}

// ---------------- K7: conv GEMM + BN + relu + residual -> x2 (in-place in hg) ----------------
__global__ __launch_bounds__(256) void k7_conv(const float* __restrict__ agg,
    float* __restrict__ hg, const float* __restrict__ Wc,
    const float* __restrict__ cb, const float* __restrict__ g1,
    const float* __restrict__ b1)
{
  const int t = threadIdx.x;
  const int R0 = blockIdx.x * 32;
  const int r0 = (t >> 5) * 4;
  const int c0 = (t & 31) * 4;
  float acc[4][4] = {};
  for (int k0 = 0; k0 < H; k0 += 4) {
    float ax[4][4];
#pragma unroll
    for (int r = 0; r < 4; ++r) {
      float4 a4 = ld4(agg + (size_t)(R0 + r0 + r) * H + k0);
      ax[r][0] = a4.x; ax[r][1] = a4.y; ax[r][2] = a4.z; ax[r][3] = a4.w;
    }
#pragma unroll
    for (int kk = 0; kk < 4; ++kk) {
      float4 w = ld4(Wc + (size_t)(k0 + kk) * H + c0);
#pragma unroll
      for (int r = 0; r < 4; ++r) {
        float av = ax[r][kk];
        acc[r][0] += av * w.x; acc[r][1] += av * w.y;
        acc[r][2] += av * w.z; acc[r][3] += av * w.w;
      }
    }
  }
#pragma unroll
  for (int r = 0; r < 4; ++r) {
    size_t off = (size_t)(R0 + r0 + r) * H + c0;
    float4 res = ld4(hg + off);
    float rsv[4] = {res.x, res.y, res.z, res.w};
    float o[4];
#pragma unroll
    for (int j = 0; j < 4; ++j) {
      float v = (acc[r][j] + cb[c0 + j]) * IBN * g1[c0 + j] + b1[c0 + j];
      v = v > 0.f ? v : 0.f;
      o[j] = v + rsv[j];
    }
    st4(hg + off, make_float4(o[0], o[1], o[2], o[3]));
  }
}

// ---------------- K8: out = (0.8*x2 + 0.2*x1) @ fc_w + fc_b ----------------
__global__ __launch_bounds__(256) void k8_out(const float* __restrict__ ht,
    const float* __restrict__ hg, const float* __restrict__ W,
    const float* __restrict__ bias, float* __restrict__ out)
{
  const int t = threadIdx.x;
  const int R0 = blockIdx.x * 32;
  const int rr0 = (t >> 4) * 2;
  const int c0 = (t & 15) * 4;
  float acc[2][4] = {};
  for (int k0 = 0; k0 < H; k0 += 4) {
    float ax[2][4];
#pragma unroll
    for (int r = 0; r < 2; ++r) {
      size_t off = (size_t)(R0 + rr0 + r) * H + k0;
      float4 a1 = ld4(ht + off);
      float4 a2 = ld4(hg + off);
      ax[r][0] = 0.2f * a1.x + 0.8f * a2.x;
      ax[r][1] = 0.2f * a1.y + 0.8f * a2.y;
      ax[r][2] = 0.2f * a1.z + 0.8f * a2.z;
      ax[r][3] = 0.2f * a1.w + 0.8f * a2.w;
    }
#pragma unroll
    for (int kk = 0; kk < 4; ++kk) {
      float4 w = ld4(W + (size_t)(k0 + kk) * C + c0);
#pragma unroll
      for (int r = 0; r < 2; ++r) {
        float av = ax[r][kk];
        acc[r][0] += av * w.x; acc[r][1] += av * w.y;
        acc[r][2] += av * w.z; acc[r][3] += av * w.w;
      }
    }
  }
#pragma unroll
  for (int r = 0; r < 2; ++r) {
    float o[4];
#pragma unroll
    for (int j = 0; j < 4; ++j) o[j] = acc[r][j] + bias[c0 + j];
    st4(out + (size_t)(R0 + rr0 + r) * C + c0, make_float4(o[0], o[1], o[2], o[3]));
  }
}

// ---------------- launch ----------------
extern "C" void kernel_launch(void* const* d_in, const int* in_sizes, int n_in,
                              void* d_out, int out_size, void* d_ws, size_t ws_size,
                              hipStream_t stream) {
  (void)in_sizes; (void)n_in; (void)out_size; (void)ws_size;
  const float* x       = (const float*)d_in[0];
  const int*   ei      = (const int*)d_in[1];
  const float* t_fc_w  = (const float*)d_in[2];
  const float* t_fc_b  = (const float*)d_in[3];
  const float* t_ln0_g = (const float*)d_in[4];
  const float* t_ln0_b = (const float*)d_in[5];
  const float* t_wq_w  = (const float*)d_in[6];
  const float* t_wq_b  = (const float*)d_in[7];
  const float* t_wk_w  = (const float*)d_in[8];
  const float* t_wk_b  = (const float*)d_in[9];
  const float* t_wv_w  = (const float*)d_in[10];
  const float* t_wv_b  = (const float*)d_in[11];
  const float* t_ln1_g = (const float*)d_in[12];
  const float* t_ln1_b = (const float*)d_in[13];
  const float* g_fc_w  = (const float*)d_in[14];
  const float* g_fc_b  = (const float*)d_in[15];
  const float* g_bn0_g = (const float*)d_in[16];
  const float* g_bn0_b = (const float*)d_in[17];
  const float* g_cv_w  = (const float*)d_in[18];
  const float* g_cv_b  = (const float*)d_in[19];
  const float* g_bn1_g = (const float*)d_in[20];
  const float* g_bn1_b = (const float*)d_in[21];
  const float* fc_w    = (const float*)d_in[22];
  const float* fc_b    = (const float*)d_in[23];

  float* W    = (float*)d_ws;
  float* ht   = W + OFF_HT;
  float* hg   = W + OFF_HG;
  float* agg  = W + OFF_AGG;       // first: gram partials; then: gather output
  int*   cnt  = (int*)(W + OFF_CNT);
  float* s    = W + OFF_S;
  float* G    = W + OFF_G;
  int*   ptr  = (int*)(W + OFF_PTR);
  int*   cur  = (int*)(W + OFF_CUR);
  int*   bsum = (int*)(W + OFF_BS);
  int*   srow = (int*)(W + OFF_SROW);
  float* sval = W + OFF_SVAL;
  float* gw   = W + OFF_GWV;
  float* kv   = W + OFF_KV;
  float* ksum = W + OFF_KSUM;
  float* vsum = W + OFF_VSUM;
  float* qsum = W + OFF_QSUM;
  float* sc   = W + OFF_SC;
  unsigned short* Bt2 = (unsigned short*)(W + OFF_B);
  float* cc   = W + OFF_CC;
  float* u    = W + OFF_U;
  float* u0   = W + OFF_U0;
  unsigned short* Bt = (unsigned short*)(W + OFF_BT);

  hipMemsetAsync(cnt, 0, N * sizeof(int), stream);

  // weight pack for MFMA k1 (gload_lds tile-order layout)
  k0_cvt<<<512, 256, 0, stream>>>(t_fc_w, g_fc_w, Bt);

  // graph branch CSR build (independent of k1)
  k5_deg<<<(E + 255) / 256, 256, 0, stream>>>(ei, cnt);
  k_scan1<<<NB1024, 256, 0, stream>>>(cnt, bsum);
  k_scan2<<<1, 128, 0, stream>>>(bsum);
  k_scan3<<<NB1024, 256, 0, stream>>>(cnt, bsum, ptr, cur);
  k6a_place<<<E / 256, 256, 0, stream>>>(ei, cnt, cur, srow, sval);

  k1_mfma<<<(N + 127) / 128, 512, 0, stream>>>(x, Bt, t_fc_b, t_ln0_g, t_ln0_b,
                                               g_fc_b, g_bn0_g, g_bn0_b, ht, hg);
  // trans reductions FIRST (partials live in agg, freed before gather overwrites)
  k2_gram<<<NB_GRAM, 256, 0, stream>>>(ht, agg, agg + SP_BASE);
  k2r_reduce<<<64, 256, 0, stream>>>(agg, agg + SP_BASE, G, s);
  // graph aggregation (gather) — overwrites agg
  k6b_gather<<<N / 8, 256, 0, stream>>>(ptr, cnt, srow, sval, hg, agg);
  k3a_gw<<<384, 256, 0, stream>>>(G, t_wv_w, t_wk_w, t_wq_w, gw);
  k3k_sums<<<3, 256, 0, stream>>>(s, t_wk_w, t_wk_b, t_wv_w, t_wv_b, t_wq_w, t_wq_b,
                                  ksum, vsum, qsum);
  k3b_kv<<<128, 256, 0, stream>>>(gw, s, t_wk_w, t_wk_b, t_wv_b, vsum, kv);
  k3c_ssq<<<1, 256, 0, stream>>>(t_wk_w, gw + 32768, t_wq_w, gw + 65536,
                                 t_wk_b, ksum, t_wq_b, qsum, sc);
  k3d_B<<<128, 256, 0, stream>>>(t_wq_w, kv, t_wv_w, sc, Bt2);
  k3e_small<<<1, 512, 0, stream>>>(t_wq_b, kv, t_wv_b, t_wq_w, ksum, sc, cc, u, u0);
  k4_mfma<<<(N + 63) / 64, 256, 0, stream>>>(ht, Bt2, cc, u, u0, t_ln1_g, t_ln1_b);
  // graph tail + output
  k7_conv<<<N / 32, 256, 0, stream>>>(agg, hg, g_cv_w, g_cv_b, g_bn1_g, g_bn1_b);
  k8_out<<<N / 32, 256, 0, stream>>>(ht, hg, fc_w, fc_b, (float*)d_out);
}

// Round 6
// 1123.475 us; speedup vs baseline: 1.0669x; 1.0191x over previous
//
#include <hip/hip_runtime.h>

// ---------------- problem constants ----------------
constexpr int N = 100000;
constexpr int F = 512;
constexpr int H = 128;
constexpr int E = 1600000;
constexpr int C = 64;
constexpr float EPS = 1e-5f;
constexpr float NF = 100000.0f;     // number of nodes as float
constexpr float IBN = 0.999995000037f; // 1/sqrt(1+1e-5)

// ---------------- workspace layout (float offsets) ----------------
constexpr size_t OFF_HT   = 0;                     // [N,H] trans hidden, later x1 (in-place)
constexpr size_t OFF_HG   = 12800000;              // [N,H] graph hidden (residual input to conv)
constexpr size_t OFF_AGG  = 25600000;              // [N,H]; FIRST reused as gram partials, THEN gather output
constexpr size_t OFF_CNT  = 38400000;              // int[N] in-degree  (zeroed)
constexpr size_t OFF_S    = 38500000;              // [128] colsum (written by k2r)
constexpr size_t OFF_G    = 38500128;              // [128,128] gram (written by k2r)
constexpr size_t OFF_PTR  = 38516512;              // int[N] CSR bucket starts
constexpr size_t OFF_CUR  = 38616512;              // int[N] placement cursors
constexpr size_t OFF_BS   = 38716512;              // int[128] scan block offsets
constexpr size_t OFF_SROW = 38716640;              // int[E] sorted src rows
constexpr size_t OFF_SVAL = 40316640;              // float[E] sorted edge weights
constexpr size_t OFF_GWV  = 41916640;              // 3 x [128,256]: G@Wv, G@Wk, G@Wq
constexpr size_t OFF_KV   = OFF_GWV + 3 * 32768;   // [2,128,128] kv_raw
constexpr size_t OFF_KSUM = OFF_KV + 32768;        // [256]
constexpr size_t OFF_VSUM = OFF_KSUM + 256;        // [256]
constexpr size_t OFF_QSUM = OFF_VSUM + 256;        // [256]
constexpr size_t OFF_SC   = OFF_QSUM + 256;        // [4]
constexpr size_t OFF_B    = OFF_SC + 4;            // bf16 Bt2[256][128] (16384 floats used of 32768)
constexpr size_t OFF_CC   = OFF_B + 32768;         // [256]
constexpr size_t OFF_U    = OFF_CC + 256;          // [128,2]
constexpr size_t OFF_U0   = OFF_U + 256;           // [2] (+2 pad)
constexpr size_t OFF_BT   = OFF_U0 + 4;            // bf16[16 kt][1024 chunks][8] = 65536 floats

constexpr int NB1024 = (N + 1023) / 1024;          // 98 scan blocks
constexpr int NB_GRAM = (N + 255) / 256;           // 391 gram blocks
constexpr size_t SP_BASE = (size_t)NB_GRAM * 16384; // colsum partials offset inside agg

typedef __attribute__((ext_vector_type(8))) short short8;
typedef __attribute__((ext_vector_type(4))) float floatx4;

__device__ __forceinline__ float4 ld4(const float* p) {
  return *reinterpret_cast<const float4*>(p);
}
__device__ __forceinline__ void st4(float* p, float4 v) {
  *reinterpret_cast<float4*>(p) = v;
}
__device__ __forceinline__ unsigned short f2bf(float f) {
  unsigned u = __float_as_uint(f);
  u += 0x7fff + ((u >> 16) & 1);       // RNE
  return (unsigned short)(u >> 16);
}
__device__ __forceinline__ float bf2f(unsigned short h) {
  return __uint_as_float((unsigned)h << 16);
}
// async global->LDS 16B copy (per-lane global addr, wave-uniform LDS base; HW adds lane*16)
__device__ __forceinline__ void gl_lds16(const unsigned short* g, unsigned short* l) {
  __builtin_amdgcn_global_load_lds(
      (const __attribute__((address_space(1))) unsigned int*)g,
      (__attribute__((address_space(3))) unsigned int*)l, 16, 0, 0);
}

// ---------------- K0: pack Wt||Wg -> bf16 Bt in gload_lds tile order ----------------
// Per K-step kt (32 wide), tile = 1024 chunks of 16B (8 bf16).
// Logical chunk for (k,n): g=(k>>3)&3, chunk = g*256 + ((n + 2g) & 255), element e = k&7.
__global__ __launch_bounds__(256) void k0_cvt(const float* __restrict__ Wt,
    const float* __restrict__ Wg, unsigned short* __restrict__ Bt)
{
  const int idx = blockIdx.x * 256 + threadIdx.x;   // < 131072
  const int k = idx >> 8;       // 0..511
  const int n = idx & 255;      // 0..255
  float v = (n < 128) ? Wt[(size_t)k * H + n] : Wg[(size_t)k * H + (n - 128)];
  const int kt = k >> 5;            // 0..15
  const int g  = (k >> 3) & 3;      // 0..3
  const int e  = k & 7;
  const int chunk = g * 256 + ((n + 2 * g) & 255);
  Bt[(((size_t)kt * 1024 + chunk) << 3) + e] = f2bf(v);
}

// ---------------- K1: MFMA fused fc GEMMs, 512-thread 2-phase dbuf pipeline ----------------
// 128 rows/block, 8 waves (4x2 wave grid over 128x256 output), BK=32, 16 K-steps.
// Epilogue fully in-register (shfl LN). VGPR=64 -> 8 waves/SIMD possible; LDS 53KB -> 3 blocks/CU.
__global__ __launch_bounds__(512, 4) void k1_mfma(
    const float* __restrict__ x, const unsigned short* __restrict__ Bt,
    const float* __restrict__ bt, const float* __restrict__ lng, const float* __restrict__ lnb,
    const float* __restrict__ bgv, const float* __restrict__ bng, const float* __restrict__ bnb,
    float* __restrict__ ht, float* __restrict__ hg)
{
  __shared__ __align__(16) struct {
    unsigned short A[2][128 * 40];   // 20480 B (32 data + 8 pad shorts per row)
    unsigned short B[2][8192];       // 32768 B (1024 chunks of 16B per buffer)
  } sm;                              // 53248 B total
  const int t = threadIdx.x;        // 0..511
  const int lane = t & 63;
  const int w = t >> 6;             // 0..7
  const int rq = (w >> 1) * 32;     // wave row base: 0/32/64/96
  const int cq = (w & 1) * 128;     // wave col base: 0/128
  const int g = lane >> 4;          // 0..3
  const int m = lane & 15;
  const int M0 = blockIdx.x * 128;

  floatx4 acc[2][8];
#pragma unroll
  for (int rt = 0; rt < 2; ++rt)
#pragma unroll
    for (int ct = 0; ct < 8; ++ct) acc[rt][ct] = (floatx4){0.f, 0.f, 0.f, 0.f};

  // A staging: thread t covers row t>>2 (0..127), 8 cols at (t&3)*8 within the 32-wide K slice
  const int srow = t >> 2;
  const int scol8 = (t & 3) * 8;
  const int grow = (M0 + srow < N) ? (M0 + srow) : (N - 1);
  const float* xp = x + (size_t)grow * F + scol8;

  // B fragment chunk base (g-rotated)
  const int mb = cq + m + 2 * g;    // + ct*16, & 255 at use
  const int ldsw = (w << 6);        // wave's 64-chunk segment base

  // ---- prologue: stage kt=0 into buf 0 ----
  {
#pragma unroll
    for (int i = 0; i < 2; ++i)
      gl_lds16(Bt + (((size_t)(i * 512 + t)) << 3),
               &sm.B[0][(size_t)(i * 512 + ldsw) << 3]);
    float4 a0 = ld4(xp), a1 = ld4(xp + 4);
    ushort4 p0, p1;
    p0.x = f2bf(a0.x); p0.y = f2bf(a0.y); p0.z = f2bf(a0.z); p0.w = f2bf(a0.w);
    p1.x = f2bf(a1.x); p1.y = f2bf(a1.y); p1.z = f2bf(a1.z); p1.w = f2bf(a1.w);
    *(ushort4*)(sm.A[0] + srow * 40 + scol8) = p0;
    *(ushort4*)(sm.A[0] + srow * 40 + scol8 + 4) = p1;
  }
  __syncthreads();   // drains vmcnt (incl. gload_lds) + lgkmcnt

#pragma unroll 2
  for (int kt = 0; kt < 16; ++kt) {
    const int cur = kt & 1, nxt = cur ^ 1;
    float4 a0, a1;
    const bool more = (kt + 1 < 16);
    if (more) {
      // issue next B tile (async to LDS) and next A slice (to regs)
#pragma unroll
      for (int i = 0; i < 2; ++i)
        gl_lds16(Bt + (((size_t)(kt + 1) * 1024 + i * 512 + t) << 3),
                 &sm.B[nxt][(size_t)(i * 512 + ldsw) << 3]);
      a0 = ld4(xp + (kt + 1) * 32);
      a1 = ld4(xp + (kt + 1) * 32 + 4);
    }
    // compute current tile
    {
      const unsigned short* Ab = sm.A[cur];
      const unsigned short* Bb = sm.B[cur];
      short8 af[2], bf[8];
#pragma unroll
      for (int rt = 0; rt < 2; ++rt)
        af[rt] = *(const short8*)(Ab + (rq + rt * 16 + m) * 40 + g * 8);
#pragma unroll
      for (int ct = 0; ct < 8; ++ct) {
        const int chunk = g * 256 + ((mb + ct * 16) & 255);
        bf[ct] = *(const short8*)(Bb + ((size_t)chunk << 3));
      }
#pragma unroll
      for (int rt = 0; rt < 2; ++rt)
#pragma unroll
        for (int ct = 0; ct < 8; ++ct)
          acc[rt][ct] = __builtin_amdgcn_mfma_f32_16x16x32_bf16(af[rt], bf[ct], acc[rt][ct], 0, 0, 0);
    }
    if (more) {
      ushort4 p0, p1;
      p0.x = f2bf(a0.x); p0.y = f2bf(a0.y); p0.z = f2bf(a0.z); p0.w = f2bf(a0.w);
      p1.x = f2bf(a1.x); p1.y = f2bf(a1.y); p1.z = f2bf(a1.z); p1.w = f2bf(a1.w);
      *(ushort4*)(sm.A[nxt] + srow * 40 + scol8) = p0;
      *(ushort4*)(sm.A[nxt] + srow * 40 + scol8 + 4) = p1;
    }
    __syncthreads();   // single drain per K-step: buf[nxt] complete, buf[cur] free
  }

  // ---- epilogue, fully in-register. C/D layout: col = ct*16+m, row = rt*16+g*4+r ----
  if (cq == 0) {
    // ht half: bias + LN + relu; wave holds the FULL 128-col row -> shfl reduce
    float bt_l[8], lng_l[8], lnb_l[8];
#pragma unroll
    for (int ct = 0; ct < 8; ++ct) {
      bt_l[ct] = bt[ct * 16 + m];
      lng_l[ct] = lng[ct * 16 + m];
      lnb_l[ct] = lnb[ct * 16 + m];
    }
#pragma unroll
    for (int rt = 0; rt < 2; ++rt) {
#pragma unroll
      for (int r = 0; r < 4; ++r) {
        float sum = 0.f, sq = 0.f;
#pragma unroll
        for (int ct = 0; ct < 8; ++ct) {
          float v = acc[rt][ct][r] + bt_l[ct];
          acc[rt][ct][r] = v;
          sum += v; sq += v * v;
        }
        // reduce across the 16-lane m-group (masks 1,2,4,8 stay within group)
#pragma unroll
        for (int off = 1; off < 16; off <<= 1) {
          sum += __shfl_xor(sum, off, 64);
          sq  += __shfl_xor(sq,  off, 64);
        }
        const float mu = sum * (1.f / H);
        const float rs = rsqrtf(sq * (1.f / H) - mu * mu + EPS);
        const int row = M0 + rq + rt * 16 + g * 4 + r;
        if (row < N) {
          float* hp = ht + (size_t)row * H + m;
#pragma unroll
          for (int ct = 0; ct < 8; ++ct) {
            float o = (acc[rt][ct][r] - mu) * rs * lng_l[ct] + lnb_l[ct];
            hp[ct * 16] = o > 0.f ? o : 0.f;
          }
        }
      }
    }
  } else {
    // hg half: bias + BN + relu, elementwise
#pragma unroll
    for (int ct = 0; ct < 8; ++ct) {
      const int c2 = ct * 16 + m;
      const float s1 = IBN * bng[c2], b0 = bgv[c2], b2v = bnb[c2];
#pragma unroll
      for (int rt = 0; rt < 2; ++rt) {
#pragma unroll
        for (int r = 0; r < 4; ++r) {
          const int row = M0 + rq + rt * 16 + g * 4 + r;
          if (row < N) {
            float v = (acc[rt][ct][r] + b0) * s1 + b2v;
            hg[(size_t)row * H + c2] = v > 0.f ? v : 0.f;
          }
        }
      }
    }
  }
}

// ---------------- K2: gram + colsum partials, NO atomics ----------------
__global__ __launch_bounds__(256) void k2_gram(const float* __restrict__ ht,
                                               float* __restrict__ gp,   // [NB_GRAM][16384]
                                               float* __restrict__ sp)   // [NB_GRAM][128]
{
  const int t = threadIdx.x;
  const int b = blockIdx.x;
  const int base = b * 256;
  const int nend = (base + 256 < N) ? base + 256 : N;
  const int r0 = (t >> 4) * 8;
  const int c0 = (t & 15) * 8;
  float acc[8][8] = {};
  float colacc[8] = {};
  const bool do_col = (t < 16);
  int n = base;
  for (; n + 1 < nend; n += 2) {
    const float* hp0 = ht + (size_t)n * H;
    const float* hp1 = hp0 + H;
    float4 a00 = ld4(hp0 + r0), a01 = ld4(hp0 + r0 + 4);
    float4 b00 = ld4(hp0 + c0), b01 = ld4(hp0 + c0 + 4);
    float4 a10 = ld4(hp1 + r0), a11 = ld4(hp1 + r0 + 4);
    float4 b10 = ld4(hp1 + c0), b11 = ld4(hp1 + c0 + 4);
    float a0[8] = {a00.x, a00.y, a00.z, a00.w, a01.x, a01.y, a01.z, a01.w};
    float b0[8] = {b00.x, b00.y, b00.z, b00.w, b01.x, b01.y, b01.z, b01.w};
    float a1[8] = {a10.x, a10.y, a10.z, a10.w, a11.x, a11.y, a11.z, a11.w};
    float b1[8] = {b10.x, b10.y, b10.z, b10.w, b11.x, b11.y, b11.z, b11.w};
    if (do_col) {
#pragma unroll
      for (int j = 0; j < 8; ++j) colacc[j] += b0[j] + b1[j];
    }
#pragma unroll
    for (int i = 0; i < 8; ++i)
#pragma unroll
      for (int j = 0; j < 8; ++j)
        acc[i][j] += a0[i] * b0[j] + a1[i] * b1[j];
  }
  if (n < nend) {
    const float* hp0 = ht + (size_t)n * H;
    float4 a00 = ld4(hp0 + r0), a01 = ld4(hp0 + r0 + 4);
    float4 b00 = ld4(hp0 + c0), b01 = ld4(hp0 + c0 + 4);
    float a0[8] = {a00.x, a00.y, a00.z, a00.w, a01.x, a01.y, a01.z, a01.w};
    float b0[8] = {b00.x, b00.y, b00.z, b00.w, b01.x, b01.y, b01.z, b01.w};
    if (do_col) {
#pragma unroll
      for (int j = 0; j < 8; ++j) colacc[j] += b0[j];
    }
#pragma unroll
    for (int i = 0; i < 8; ++i)
#pragma unroll
      for (int j = 0; j < 8; ++j)
        acc[i][j] += a0[i] * b0[j];
  }
  float* g = gp + (size_t)b * 16384;
#pragma unroll
  for (int i = 0; i < 8; ++i) {
    st4(&g[(r0 + i) * H + c0], make_float4(acc[i][0], acc[i][1], acc[i][2], acc[i][3]));
    st4(&g[(r0 + i) * H + c0 + 4], make_float4(acc[i][4], acc[i][5], acc[i][6], acc[i][7]));
  }
  if (do_col) {
    float* spb = sp + (size_t)b * 128;
    st4(&spb[c0], make_float4(colacc[0], colacc[1], colacc[2], colacc[3]));
    st4(&spb[c0 + 4], make_float4(colacc[4], colacc[5], colacc[6], colacc[7]));
  }
}

// ---------------- K2r: reduce partials -> G, s ----------------
__global__ __launch_bounds__(256) void k2r_reduce(const float* __restrict__ gp,
    const float* __restrict__ sp, float* __restrict__ G, float* __restrict__ s)
{
  const int i = blockIdx.x * 256 + threadIdx.x;   // < 16384
  float s0 = 0.f, s1 = 0.f, s2 = 0.f, s3 = 0.f;
  int b = 0;
  for (; b + 3 < NB_GRAM; b += 4) {
    s0 += gp[(size_t)b * 16384 + i];
    s1 += gp[(size_t)(b + 1) * 16384 + i];
    s2 += gp[(size_t)(b + 2) * 16384 + i];
    s3 += gp[(size_t)(b + 3) * 16384 + i];
  }
  for (; b < NB_GRAM; ++b) s0 += gp[(size_t)b * 16384 + i];
  G[i] = (s0 + s1) + (s2 + s3);
  if (blockIdx.x == 0 && threadIdx.x < 128) {
    float t0 = 0.f, t1 = 0.f;
    int bb = 0;
    for (; bb + 1 < NB_GRAM; bb += 2) {
      t0 += sp[(size_t)bb * 128 + threadIdx.x];
      t1 += sp[(size_t)(bb + 1) * 128 + threadIdx.x];
    }
    for (; bb < NB_GRAM; ++bb) t0 += sp[(size_t)bb * 128 + threadIdx.x];
    s[threadIdx.x] = t0 + t1;
  }
}

// ---------------- K3a: GW = G @ {Wv, Wk, Wq} ----------------
__global__ __launch_bounds__(256) void k3a_gw(const float* __restrict__ G,
    const float* __restrict__ Wv, const float* __restrict__ Wk,
    const float* __restrict__ Wq, float* __restrict__ GW)
{
  const int flat = blockIdx.x * 256 + threadIdx.x;   // < 98304
  const int w = flat >> 15;
  const int rem = flat & 32767;
  const int i = rem >> 8;
  const int j = rem & 255;
  const float* W = (w == 0) ? Wv : (w == 1) ? Wk : Wq;
  float sum = 0.f;
#pragma unroll 8
  for (int k = 0; k < H; ++k) sum += G[i * H + k] * W[k * 256 + j];
  GW[flat] = sum;
}

// ---------------- K3k: ksum/vsum/qsum = s @ W + N*b ----------------
__global__ __launch_bounds__(256) void k3k_sums(const float* __restrict__ s,
    const float* __restrict__ Wk, const float* __restrict__ bk,
    const float* __restrict__ Wv, const float* __restrict__ bv,
    const float* __restrict__ Wq, const float* __restrict__ bq,
    float* __restrict__ ksum, float* __restrict__ vsum, float* __restrict__ qsum)
{
  const int flat = blockIdx.x * 256 + threadIdx.x;   // < 768
  const int w = flat >> 8;
  const int j = flat & 255;
  const float* W = (w == 0) ? Wk : (w == 1) ? Wv : Wq;
  const float* b = (w == 0) ? bk : (w == 1) ? bv : bq;
  float* out = (w == 0) ? ksum : (w == 1) ? vsum : qsum;
  float sum = 0.f;
#pragma unroll 8
  for (int k = 0; k < H; ++k) sum += s[k] * W[k * 256 + j];
  out[j] = sum + NF * b[j];
}

// ---------------- K3b: kv_raw[h,m,d] ----------------
__global__ __launch_bounds__(256) void k3b_kv(const float* __restrict__ GWv,
    const float* __restrict__ s, const float* __restrict__ Wk,
    const float* __restrict__ bk, const float* __restrict__ bv,
    const float* __restrict__ vsum, float* __restrict__ kv)
{
  const int flat = blockIdx.x * 256 + threadIdx.x;   // < 32768
  const int h = flat >> 14;
  const int m = (flat >> 7) & 127;
  const int d = flat & 127;
  float s1 = 0.f, s2 = 0.f;
#pragma unroll 4
  for (int k = 0; k < H; ++k) {
    float wkv = Wk[k * 256 + h * 128 + m];
    s1 += wkv * GWv[k * 256 + h * 128 + d];
    s2 += wkv * s[k];
  }
  kv[flat] = s1 + s2 * bv[h * 128 + d] + bk[h * 128 + m] * vsum[h * 128 + d];
}

// ---------------- K3c: ssq_q, ssq_k, inv ----------------
__global__ __launch_bounds__(256) void k3c_ssq(
    const float* __restrict__ Wk, const float* __restrict__ GWk,
    const float* __restrict__ Wq, const float* __restrict__ GWq,
    const float* __restrict__ bk, const float* __restrict__ ksum,
    const float* __restrict__ bq, const float* __restrict__ qsum,
    float* __restrict__ sc)
{
  __shared__ float red[512];
  const int t = threadIdx.x;
  float pk = 0.f, pq = 0.f;
  for (int i = t; i < 32768; i += 256) {
    pk += Wk[i] * GWk[i];
    pq += Wq[i] * GWq[i];
  }
  pk += 2.f * bk[t] * ksum[t] - NF * bk[t] * bk[t];
  pq += 2.f * bq[t] * qsum[t] - NF * bq[t] * bq[t];
  red[t] = pk; red[256 + t] = pq;
  __syncthreads();
  for (int off = 128; off > 0; off >>= 1) {
    if (t < off) { red[t] += red[t + off]; red[256 + t] += red[256 + t + off]; }
    __syncthreads();
  }
  if (t == 0) {
    float ssq_k = red[0], ssq_q = red[256];
    sc[0] = ssq_q; sc[1] = ssq_k;
    sc[2] = rsqrtf(ssq_q * ssq_k);   // 1/(||q|| * ||k||)
  }
}

// ---------------- K3d: B = Wq @ kv * inv + N*Wv -> packed bf16 Bt2[n=256][k=128] ----------------
__global__ __launch_bounds__(256) void k3d_B(const float* __restrict__ Wq,
    const float* __restrict__ kv, const float* __restrict__ Wv,
    const float* __restrict__ sc, unsigned short* __restrict__ Bt2)
{
  const int flat = blockIdx.x * 256 + threadIdx.x;   // < 32768
  const int i = flat >> 8;       // 0..127 : k-dim (h index)
  const int j = flat & 255;      // 0..255 : col (head*128 + d)
  const int h = j >> 7;
  const int d = j & 127;
  const float inv = sc[2];
  float sum = 0.f;
#pragma unroll 4
  for (int m = 0; m < H; ++m)
    sum += Wq[i * 256 + h * 128 + m] * kv[h * 16384 + m * 128 + d];
  Bt2[(size_t)j * H + i] = f2bf(sum * inv + NF * Wv[i * 256 + j]);
}

// ---------------- K3e: c, u, u0 ----------------
__global__ __launch_bounds__(512) void k3e_small(const float* __restrict__ bq,
    const float* __restrict__ kv, const float* __restrict__ bv,
    const float* __restrict__ Wq, const float* __restrict__ ksum,
    const float* __restrict__ sc, float* __restrict__ cc,
    float* __restrict__ u, float* __restrict__ u0)
{
  const int t = threadIdx.x;
  const float inv = sc[2];
  if (t < 256) {
    const int h = t >> 7, d = t & 127;
    float sum = 0.f;
    for (int m = 0; m < H; ++m) sum += bq[h * 128 + m] * kv[h * 16384 + m * 128 + d];
    cc[t] = sum * inv + NF * bv[t];
  } else {
    const int q = t - 256;
    const int i = q >> 1, h = q & 1;
    float sum = 0.f;
    for (int m = 0; m < H; ++m) sum += Wq[i * 256 + h * 128 + m] * ksum[h * 128 + m];
    u[i * 2 + h] = sum * inv;
  }
  if (t < 2) {
    float sum = 0.f;
    for (int m = 0; m < H; ++m) sum += bq[t * 128 + m] * ksum[t * 128 + m];
    u0[t] = sum * inv + NF;
  }
}

// ---------------- K4: MFMA attention apply + residual + LN -> x1 (in-place in ht) ----------------
// 64-row tile; 4 waves; each wave: 16 rows x all 256 cols (head combine is in-lane: ct vs ct+8)
__global__ __launch_bounds__(256) void k4_mfma(float* __restrict__ ht,
    const unsigned short* __restrict__ Bt2, const float* __restrict__ cc,
    const float* __restrict__ u, const float* __restrict__ u0,
    const float* __restrict__ lng, const float* __restrict__ lnb)
{
  __shared__ __align__(16) union {
    unsigned short A[64 * 136];       // 17408 B (bf16 ht tile)
    float lns[64 * 132];              // 33792 B (LN staging)
  } sm;
  __shared__ float u_s[256];
  __shared__ float rden_s[128];       // [row][head]
  __shared__ float mu_s[64], rs_s[64];
  const int t = threadIdx.x;
  const int lane = t & 63;
  const int w = t >> 6;
  const int rq = w * 16;              // wave row base 0/16/32/48
  const int g = lane >> 4;
  const int m = lane & 15;
  const int M0 = blockIdx.x * 64;

  // stage A: ht rows fp32 -> bf16 LDS (K=128 fits entirely)
  {
    const int srow = t >> 2;          // 0..63
    const int scol = (t & 3) * 32;    // 0,32,64,96
    const int grow = (M0 + srow < N) ? (M0 + srow) : (N - 1);
    const float* xp = ht + (size_t)grow * H + scol;
#pragma unroll
    for (int j = 0; j < 8; ++j) {
      float4 a4 = ld4(xp + j * 4);
      ushort4 p;
      p.x = f2bf(a4.x); p.y = f2bf(a4.y); p.z = f2bf(a4.z); p.w = f2bf(a4.w);
      *(ushort4*)(sm.A + srow * 136 + scol + j * 4) = p;
    }
  }
  u_s[t] = u[t];
  __syncthreads();

  floatx4 acc[16];
#pragma unroll
  for (int ct = 0; ct < 16; ++ct) acc[ct] = (floatx4){0.f, 0.f, 0.f, 0.f};
#pragma unroll
  for (int kk = 0; kk < 128; kk += 32) {
    short8 af = *(const short8*)(sm.A + (rq + m) * 136 + kk + g * 8);
#pragma unroll
    for (int ct = 0; ct < 16; ++ct) {
      short8 bf = *(const short8*)(Bt2 + (size_t)(ct * 16 + m) * H + kk + g * 8);
      acc[ct] = __builtin_amdgcn_mfma_f32_16x16x32_bf16(af, bf, acc[ct], 0, 0, 0);
    }
  }
  // denominators (waves 0,1): row=t>>1, head=t&1
  if (t < 128) {
    const int row = t >> 1, head = t & 1;
    float den = u0[head];
    for (int k = 0; k < H; ++k)
      den += bf2f(sm.A[row * 136 + k]) * u_s[k * 2 + head];
    rden_s[row * 2 + head] = 0.5f / den;   // mean-over-heads folded
  }
  __syncthreads();   // A fully consumed; lns may now overwrite the union

  // combine heads + residual -> lns
#pragma unroll
  for (int ct = 0; ct < 8; ++ct) {
    const int d = ct * 16 + m;
    const float c0v = cc[d], c1v = cc[128 + d];
#pragma unroll
    for (int r = 0; r < 4; ++r) {
      const int row = rq + g * 4 + r;         // block-local 0..63
      const int grow = M0 + row;
      const float rd0 = rden_s[row * 2], rd1 = rden_s[row * 2 + 1];
      float attn = (acc[ct][r] + c0v) * rd0 + (acc[ct + 8][r] + c1v) * rd1;
      float hres = (grow < N) ? ht[(size_t)grow * H + d] : 0.f;
      sm.lns[row * 132 + d] = (attn + hres) * 0.5f;
    }
  }
  __syncthreads();
  if (t < 64) {
    float sum = 0.f, sq = 0.f;
    for (int c2 = 0; c2 < H; ++c2) {
      float v = sm.lns[t * 132 + c2];
      sum += v; sq += v * v;
    }
    float mu = sum * (1.f / H);
    float var = sq * (1.f / H) - mu * mu;
    mu_s[t] = mu; rs_s[t] = rsqrtf(var + EPS);
  }
  __syncthreads();
  {
    const int r = t >> 2;
    const int cb = (t & 3) * 32;
    if (M0 + r < N) {
      const float mu = mu_s[r], rs = rs_s[r];
#pragma unroll
      for (int j = 0; j < 8; ++j) {
        const int c = cb + j * 4;
        float o[4];
#pragma unroll
        for (int q = 0; q < 4; ++q) {
          float v = (sm.lns[r * 132 + c + q] - mu) * rs * lng[c + q] + lnb[c + q];
          o[q] = v > 0.f ? v : 0.f;
        }
        st4(ht + (size_t)(M0 + r) * H + c, make_float4(o[0], o[1], o[2], o[3]));
      }
    }
  }
}

// ---------------- K5: in-degree (int counts) ----------------
__global__ __launch_bounds__(256) void k5_deg(const int* __restrict__ ei,
                                              int* __restrict__ cnt)
{
  const int i = blockIdx.x * 256 + threadIdx.x;
  if (i < E) atomicAdd(&cnt[ei[E + i]], 1);
}

// ---------------- scan1: per-1024-chunk sums ----------------
__global__ __launch_bounds__(256) void k_scan1(const int* __restrict__ cnt,
                                               int* __restrict__ bsum)
{
  __shared__ int red[256];
  const int t = threadIdx.x;
  const int base = blockIdx.x * 1024 + t * 4;
  int s = 0;
#pragma unroll
  for (int j = 0; j < 4; ++j) {
    int idx = base + j;
    if (idx < N) s += cnt[idx];
  }
  red[t] = s;
  __syncthreads();
  for (int off = 128; off > 0; off >>= 1) {
    if (t < off) red[t] += red[t + off];
    __syncthreads();
  }
  if (t == 0) bsum[blockIdx.x] = red[0];
}

// ---------------- scan2: parallel exclusive scan of 98 block sums ----------------
__global__ __launch_bounds__(128) void k_scan2(int* __restrict__ bsum)
{
  __shared__ int sh[128];
  const int t = threadIdx.x;
  const int v = (t < NB1024) ? bsum[t] : 0;
  sh[t] = v;
  __syncthreads();
  for (int off = 1; off < 128; off <<= 1) {
    int add = (t >= off) ? sh[t - off] : 0;
    __syncthreads();
    sh[t] += add;
    __syncthreads();
  }
  if (t < NB1024) bsum[t] = sh[t] - v;   // exclusive
}

// ---------------- scan3: intra-chunk exclusive scan -> ptr, cur ----------------
__global__ __launch_bounds__(256) void k_scan3(const int* __restrict__ cnt,
    const int* __restrict__ bsum, int* __restrict__ ptr, int* __restrict__ cur)
{
  __shared__ int part[256];
  const int t = threadIdx.x;
  const int base = blockIdx.x * 1024 + t * 4;
  int v[4];
  int tsum = 0;
#pragma unroll
  for (int j = 0; j < 4; ++j) {
    int idx = base + j;
    v[j] = (idx < N) ? cnt[idx] : 0;
    tsum += v[j];
  }
  part[t] = tsum;
  __syncthreads();
  for (int off = 1; off < 256; off <<= 1) {
    int add = (t >= off) ? part[t - off] : 0;
    __syncthreads();
    part[t] += add;
    __syncthreads();
  }
  int run = bsum[blockIdx.x] + part[t] - tsum;
#pragma unroll
  for (int j = 0; j < 4; ++j) {
    int idx = base + j;
    if (idx < N) { ptr[idx] = run; cur[idx] = run; }
    run += v[j];
  }
}

// ---------------- K6a: place edges into destination buckets ----------------
__global__ __launch_bounds__(256) void k6a_place(const int* __restrict__ ei,
    const int* __restrict__ cnt, int* __restrict__ cur,
    int* __restrict__ srow, float* __restrict__ sval)
{
  const int e = blockIdx.x * 256 + threadIdx.x;
  if (e >= E) return;
  const int r = ei[e];
  const int c = ei[E + e];
  const int p = atomicAdd(&cur[c], 1);
  srow[p] = r;
  const int dr = cnt[r];
  const float dv = (float)dr * (float)cnt[c];
  sval[p] = (dr > 0) ? rsqrtf(dv) : 0.f;   // nan_to_num(inf)=0 when deg[row]==0
}

// ---------------- K6b: gather-accumulate agg[n] = sum val*hg[row], 4-deep MLP ----------------
__global__ __launch_bounds__(256) void k6b_gather(const int* __restrict__ ptr,
    const int* __restrict__ cnt, const int* __restrict__ srow,
    const float* __restrict__ sval, const float* __restrict__ hg,
    float* __restrict__ agg)
{
  const int t = threadIdx.x;
  const int n = blockIdx.x * 8 + (t >> 5);     // 8 nodes per block
  const int lane4 = (t & 31) * 4;
  const int start = ptr[n];
  const int end = start + cnt[n];
  float4 acc = make_float4(0.f, 0.f, 0.f, 0.f);
  int e = start;
  for (; e + 3 < end; e += 4) {
    int r0 = srow[e], r1 = srow[e + 1], r2 = srow[e + 2], r3 = srow[e + 3];
    float v0 = sval[e], v1 = sval[e + 1], v2 = sval[e + 2], v3 = sval[e + 3];
    float4 h0 = ld4(hg + (size_t)r0 * H + lane4);
    float4 h1 = ld4(hg + (size_t)r1 * H + lane4);
    float4 h2 = ld4(hg + (size_t)r2 * H + lane4);
    float4 h3 = ld4(hg + (size_t)r3 * H + lane4);
    acc.x += v0 * h0.x + v1 * h1.x + v2 * h2.x + v3 * h3.x;
    acc.y += v0 * h0.y + v1 * h1.y + v2 * h2.y + v3 * h3.y;
    acc.z += v0 * h0.z + v1 * h1.z + v2 * h2.z + v3 * h3.z;
    acc.w += v0 * h0.w + v1 * h1.w + v2 * h2.w + v3 * h3.w;
  }
  for (; e < end; ++e) {
    int r0 = srow[e];
    float v0 = sval[e];
    float4 h0 = ld4(hg + (size_t)r0 * H + lane4);
    acc.x += v0 * h0.x;
    acc.y += v0 * h0.y;
    acc.z += v0 * h0.z;
    acc.w += v0 * h0.w;
  }
  st4(agg + (size_t)n * H + lane4, acc);
}

// ---------------- K78: fused conv GEMM + BN + relu + residual + blend + output GEMM ----------------
// Per 32-row tile: phase 1 computes x2 = relu(BN(agg@Wc + cb)) + hg into LDS;
// phase 2 computes out = (0.2*x1 + 0.8*x2) @ fc_w + fc_b.
// Saves the hg write (51.2 MB) + hg re-read (51.2 MB) of the unfused pair.
__global__ __launch_bounds__(256) void k78_out(const float* __restrict__ agg,
    const float* __restrict__ hg, const float* __restrict__ Wc,
    const float* __restrict__ cb, const float* __restrict__ g1,
    const float* __restrict__ b1, const float* __restrict__ ht,
    const float* __restrict__ fcW, const float* __restrict__ fcB,
    float* __restrict__ out)
{
  __shared__ float x2s[32][132];     // 16896 B, stride 132 for bank spread
  const int t = threadIdx.x;
  const int R0 = blockIdx.x * 32;
  // ---- phase 1: conv + BN + relu + residual -> x2s ----
  {
    const int r0 = (t >> 5) * 4;
    const int c0 = (t & 31) * 4;
    float acc[4][4] = {};
    for (int k0 = 0; k0 < H; k0 += 4) {
      float ax[4][4];
#pragma unroll
      for (int r = 0; r < 4; ++r) {
        float4 a4 = ld4(agg + (size_t)(R0 + r0 + r) * H + k0);
        ax[r][0] = a4.x; ax[r][1] = a4.y; ax[r][2] = a4.z; ax[r][3] = a4.w;
      }
#pragma unroll
      for (int kk = 0; kk < 4; ++kk) {
        float4 w = ld4(Wc + (size_t)(k0 + kk) * H + c0);
#pragma unroll
        for (int r = 0; r < 4; ++r) {
          float av = ax[r][kk];
          acc[r][0] += av * w.x; acc[r][1] += av * w.y;
          acc[r][2] += av * w.z; acc[r][3] += av * w.w;
        }
      }
    }
#pragma unroll
    for (int r = 0; r < 4; ++r) {
      size_t off = (size_t)(R0 + r0 + r) * H + c0;
      float4 res = ld4(hg + off);
      float rsv[4] = {res.x, res.y, res.z, res.w};
#pragma unroll
      for (int j = 0; j < 4; ++j) {
        float v = (acc[r][j] + cb[c0 + j]) * IBN * g1[c0 + j] + b1[c0 + j];
        v = v > 0.f ? v : 0.f;
        x2s[r0 + r][c0 + j] = v + rsv[j];
      }
    }
  }
  __syncthreads();
  // ---- phase 2: blend + output GEMM ----
  {
    const int rr0 = (t >> 4) * 2;
    const int c0 = (t & 15) * 4;
    float acc[2][4] = {};
    for (int k0 = 0; k0 < H; k0 += 4) {
      float ax[2][4];
#pragma unroll
      for (int r = 0; r < 2; ++r) {
        size_t off = (size_t)(R0 + rr0 + r) * H + k0;
        float4 a1 = ld4(ht + off);
        ax[r][0] = 0.2f * a1.x + 0.8f * x2s[rr0 + r][k0];
        ax[r][1] = 0.2f * a1.y + 0.8f * x2s[rr0 + r][k0 + 1];
        ax[r][2] = 0.2f * a1.z + 0.8f * x2s[rr0 + r][k0 + 2];
        ax[r][3] = 0.2f * a1.w + 0.8f * x2s[rr0 + r][k0 + 3];
      }
#pragma unroll
      for (int kk = 0; kk < 4; ++kk) {
        float4 w = ld4(fcW + (size_t)(k0 + kk) * C + c0);
#pragma unroll
        for (int r = 0; r < 2; ++r) {
          float av = ax[r][kk];
          acc[r][0] += av * w.x; acc[r][1] += av * w.y;
          acc[r][2] += av * w.z; acc[r][3] += av * w.w;
        }
      }
    }
#pragma unroll
    for (int r = 0; r < 2; ++r) {
      float o[4];
#pragma unroll
      for (int j = 0; j < 4; ++j) o[j] = acc[r][j] + fcB[c0 + j];
      st4(out + (size_t)(R0 + rr0 + r) * C + c0, make_float4(o[0], o[1], o[2], o[3]));
    }
  }
}

// ---------------- launch ----------------
extern "C" void kernel_launch(void* const* d_in, const int* in_sizes, int n_in,
                              void* d_out, int out_size, void* d_ws, size_t ws_size,
                              hipStream_t stream) {
  (void)in_sizes; (void)n_in; (void)out_size; (void)ws_size;
  const float* x       = (const float*)d_in[0];
  const int*   ei      = (const int*)d_in[1];
  const float* t_fc_w  = (const float*)d_in[2];
  const float* t_fc_b  = (const float*)d_in[3];
  const float* t_ln0_g = (const float*)d_in[4];
  const float* t_ln0_b = (const float*)d_in[5];
  const float* t_wq_w  = (const float*)d_in[6];
  const float* t_wq_b  = (const float*)d_in[7];
  const float* t_wk_w  = (const float*)d_in[8];
  const float* t_wk_b  = (const float*)d_in[9];
  const float* t_wv_w  = (const float*)d_in[10];
  const float* t_wv_b  = (const float*)d_in[11];
  const float* t_ln1_g = (const float*)d_in[12];
  const float* t_ln1_b = (const float*)d_in[13];
  const float* g_fc_w  = (const float*)d_in[14];
  const float* g_fc_b  = (const float*)d_in[15];
  const float* g_bn0_g = (const float*)d_in[16];
  const float* g_bn0_b = (const float*)d_in[17];
  const float* g_cv_w  = (const float*)d_in[18];
  const float* g_cv_b  = (const float*)d_in[19];
  const float* g_bn1_g = (const float*)d_in[20];
  const float* g_bn1_b = (const float*)d_in[21];
  const float* fc_w    = (const float*)d_in[22];
  const float* fc_b    = (const float*)d_in[23];

  float* W    = (float*)d_ws;
  float* ht   = W + OFF_HT;
  float* hg   = W + OFF_HG;
  float* agg  = W + OFF_AGG;       // first: gram partials; then: gather output
  int*   cnt  = (int*)(W + OFF_CNT);
  float* s    = W + OFF_S;
  float* G    = W + OFF_G;
  int*   ptr  = (int*)(W + OFF_PTR);
  int*   cur  = (int*)(W + OFF_CUR);
  int*   bsum = (int*)(W + OFF_BS);
  int*   srow = (int*)(W + OFF_SROW);
  float* sval = W + OFF_SVAL;
  float* gw   = W + OFF_GWV;
  float* kv   = W + OFF_KV;
  float* ksum = W + OFF_KSUM;
  float* vsum = W + OFF_VSUM;
  float* qsum = W + OFF_QSUM;
  float* sc   = W + OFF_SC;
  unsigned short* Bt2 = (unsigned short*)(W + OFF_B);
  float* cc   = W + OFF_CC;
  float* u    = W + OFF_U;
  float* u0   = W + OFF_U0;
  unsigned short* Bt = (unsigned short*)(W + OFF_BT);

  hipMemsetAsync(cnt, 0, N * sizeof(int), stream);

  // weight pack for MFMA k1 (gload_lds tile-order layout)
  k0_cvt<<<512, 256, 0, stream>>>(t_fc_w, g_fc_w, Bt);

  // graph branch CSR build (independent of k1)
  k5_deg<<<(E + 255) / 256, 256, 0, stream>>>(ei, cnt);
  k_scan1<<<NB1024, 256, 0, stream>>>(cnt, bsum);
  k_scan2<<<1, 128, 0, stream>>>(bsum);
  k_scan3<<<NB1024, 256, 0, stream>>>(cnt, bsum, ptr, cur);
  k6a_place<<<E / 256, 256, 0, stream>>>(ei, cnt, cur, srow, sval);

  k1_mfma<<<(N + 127) / 128, 512, 0, stream>>>(x, Bt, t_fc_b, t_ln0_g, t_ln0_b,
                                               g_fc_b, g_bn0_g, g_bn0_b, ht, hg);
  // trans reductions FIRST (partials live in agg, freed before gather overwrites)
  k2_gram<<<NB_GRAM, 256, 0, stream>>>(ht, agg, agg + SP_BASE);
  k2r_reduce<<<64, 256, 0, stream>>>(agg, agg + SP_BASE, G, s);
  // graph aggregation (gather) — overwrites agg
  k6b_gather<<<N / 8, 256, 0, stream>>>(ptr, cnt, srow, sval, hg, agg);
  k3a_gw<<<384, 256, 0, stream>>>(G, t_wv_w, t_wk_w, t_wq_w, gw);
  k3k_sums<<<3, 256, 0, stream>>>(s, t_wk_w, t_wk_b, t_wv_w, t_wv_b, t_wq_w, t_wq_b,
                                  ksum, vsum, qsum);
  k3b_kv<<<128, 256, 0, stream>>>(gw, s, t_wk_w, t_wk_b, t_wv_b, vsum, kv);
  k3c_ssq<<<1, 256, 0, stream>>>(t_wk_w, gw + 32768, t_wq_w, gw + 65536,
                                 t_wk_b, ksum, t_wq_b, qsum, sc);
  k3d_B<<<128, 256, 0, stream>>>(t_wq_w, kv, t_wv_w, sc, Bt2);
  k3e_small<<<1, 512, 0, stream>>>(t_wq_b, kv, t_wv_b, t_wq_w, ksum, sc, cc, u, u0);
  k4_mfma<<<(N + 63) / 64, 256, 0, stream>>>(ht, Bt2, cc, u, u0, t_ln1_g, t_ln1_b);
  // fused graph tail + output
  k78_out<<<N / 32, 256, 0, stream>>>(agg, hg, g_cv_w, g_cv_b, g_bn1_g, g_bn1_b,
                                      ht, fc_w, fc_b, (float*)d_out);
}

// Round 7
// 1019.577 us; speedup vs baseline: 1.1756x; 1.1019x over previous
//
#include <hip/hip_runtime.h>

// ---------------- problem constants ----------------
constexpr int N = 100000;
constexpr int F = 512;
constexpr int H = 128;
constexpr int E = 1600000;
constexpr int C = 64;
constexpr float EPS = 1e-5f;
constexpr float NF = 100000.0f;     // number of nodes as float
constexpr float IBN = 0.999995000037f; // 1/sqrt(1+1e-5)

// ---------------- workspace layout (float offsets) ----------------
constexpr size_t OFF_HT   = 0;                     // [N,H] trans hidden, later x1 (in-place)
constexpr size_t OFF_HG   = 12800000;              // [N,H] graph hidden (residual input to conv)
constexpr size_t OFF_AGG  = 25600000;              // [N,H]; FIRST reused as gram partials, THEN gather output
constexpr size_t OFF_CNT  = 38400000;              // int[N] in-degree  (zeroed)
constexpr size_t OFF_S    = 38500000;              // [128] colsum (written by k2r)
constexpr size_t OFF_G    = 38500128;              // [128,128] gram (written by k2r)
constexpr size_t OFF_PTR  = 38516512;              // int[N] CSR bucket starts
constexpr size_t OFF_CUR  = 38616512;              // int[N] placement cursors
constexpr size_t OFF_BS   = 38716512;              // int[128] scan block offsets
constexpr size_t OFF_SROW = 38716640;              // int[E] sorted src rows
constexpr size_t OFF_SVAL = 40316640;              // float[E] sorted edge weights
constexpr size_t OFF_GWV  = 41916640;              // 3 x [128,256]: G@Wv, G@Wk, G@Wq
constexpr size_t OFF_KV   = OFF_GWV + 3 * 32768;   // [2,128,128] kv_raw
constexpr size_t OFF_KSUM = OFF_KV + 32768;        // [256]
constexpr size_t OFF_VSUM = OFF_KSUM + 256;        // [256]
constexpr size_t OFF_QSUM = OFF_VSUM + 256;        // [256]
constexpr size_t OFF_SC   = OFF_QSUM + 256;        // [4]
constexpr size_t OFF_B    = OFF_SC + 4;            // bf16 Bt2[256][128] (16384 floats used of 32768)
constexpr size_t OFF_CC   = OFF_B + 32768;         // [256]
constexpr size_t OFF_U    = OFF_CC + 256;          // [128,2]
constexpr size_t OFF_U0   = OFF_U + 256;           // [2] (+2 pad)
constexpr size_t OFF_BT   = OFF_U0 + 4;            // bf16[16 kt][1024 chunks][8] = 65536 floats
constexpr size_t OFF_WCP  = OFF_BT + 65536;        // bf16 Wc^T [128][128] = 8192 floats
constexpr size_t OFF_FCP  = OFF_WCP + 8192;        // bf16 fcW^T [64][128] = 4096 floats

constexpr int NB1024 = (N + 1023) / 1024;          // 98 scan blocks
constexpr int NB_GRAM = (N + 255) / 256;           // 391 gram blocks
constexpr size_t SP_BASE = (size_t)NB_GRAM * 16384; // colsum partials offset inside agg

typedef __attribute__((ext_vector_type(8))) short short8;
typedef __attribute__((ext_vector_type(4))) float floatx4;

__device__ __forceinline__ float4 ld4(const float* p) {
  return *reinterpret_cast<const float4*>(p);
}
__device__ __forceinline__ void st4(float* p, float4 v) {
  *reinterpret_cast<float4*>(p) = v;
}
__device__ __forceinline__ unsigned short f2bf(float f) {
  unsigned u = __float_as_uint(f);
  u += 0x7fff + ((u >> 16) & 1);       // RNE
  return (unsigned short)(u >> 16);
}
__device__ __forceinline__ float bf2f(unsigned short h) {
  return __uint_as_float((unsigned)h << 16);
}
// async global->LDS 16B copy (per-lane global addr, wave-uniform LDS base; HW adds lane*16)
__device__ __forceinline__ void gl_lds16(const unsigned short* g, unsigned short* l) {
  __builtin_amdgcn_global_load_lds(
      (const __attribute__((address_space(1))) unsigned int*)g,
      (__attribute__((address_space(3))) unsigned int*)l, 16, 0, 0);
}

// ---------------- K0: pack Wt||Wg -> bf16 Bt in gload_lds tile order ----------------
// Per K-step kt (32 wide), tile = 1024 chunks of 16B (8 bf16).
// Logical chunk for (k,n): g=(k>>3)&3, chunk = g*256 + ((n + 2g) & 255), element e = k&7.
__global__ __launch_bounds__(256) void k0_cvt(const float* __restrict__ Wt,
    const float* __restrict__ Wg, unsigned short* __restrict__ Bt)
{
  const int idx = blockIdx.x * 256 + threadIdx.x;   // < 131072
  const int k = idx >> 8;       // 0..511
  const int n = idx & 255;      // 0..255
  float v = (n < 128) ? Wt[(size_t)k * H + n] : Wg[(size_t)k * H + (n - 128)];
  const int kt = k >> 5;            // 0..15
  const int g  = (k >> 3) & 3;      // 0..3
  const int e  = k & 7;
  const int chunk = g * 256 + ((n + 2 * g) & 255);
  Bt[(((size_t)kt * 1024 + chunk) << 3) + e] = f2bf(v);
}

// ---------------- K0b: pack Wc^T and fcW^T -> bf16 (for MFMA B fragments) ----------------
__global__ __launch_bounds__(256) void k0b_cvt(const float* __restrict__ Wc,
    const float* __restrict__ fcW, unsigned short* __restrict__ Wcp,
    unsigned short* __restrict__ fcp)
{
  const int idx = blockIdx.x * 256 + threadIdx.x;   // < 24576
  if (idx < 16384) {
    const int k = idx >> 7, n = idx & 127;
    Wcp[(size_t)n * H + k] = f2bf(Wc[(size_t)k * H + n]);
  } else {
    const int q = idx - 16384;     // < 8192
    const int k = q >> 6, n = q & 63;
    fcp[(size_t)n * H + k] = f2bf(fcW[(size_t)k * C + n]);
  }
}

// ---------------- K1: MFMA fused fc GEMMs, 512-thread 2-phase dbuf pipeline ----------------
// 128 rows/block, 8 waves (4x2 wave grid over 128x256 output), BK=32, 16 K-steps.
// Epilogue fully in-register (shfl LN). VGPR=64 -> 8 waves/SIMD possible; LDS 53KB -> 3 blocks/CU.
__global__ __launch_bounds__(512, 4) void k1_mfma(
    const float* __restrict__ x, const unsigned short* __restrict__ Bt,
    const float* __restrict__ bt, const float* __restrict__ lng, const float* __restrict__ lnb,
    const float* __restrict__ bgv, const float* __restrict__ bng, const float* __restrict__ bnb,
    float* __restrict__ ht, float* __restrict__ hg)
{
  __shared__ __align__(16) struct {
    unsigned short A[2][128 * 40];   // 20480 B (32 data + 8 pad shorts per row)
    unsigned short B[2][8192];       // 32768 B (1024 chunks of 16B per buffer)
  } sm;                              // 53248 B total
  const int t = threadIdx.x;        // 0..511
  const int lane = t & 63;
  const int w = t >> 6;             // 0..7
  const int rq = (w >> 1) * 32;     // wave row base: 0/32/64/96
  const int cq = (w & 1) * 128;     // wave col base: 0/128
  const int g = lane >> 4;          // 0..3
  const int m = lane & 15;
  const int M0 = blockIdx.x * 128;

  floatx4 acc[2][8];
#pragma unroll
  for (int rt = 0; rt < 2; ++rt)
#pragma unroll
    for (int ct = 0; ct < 8; ++ct) acc[rt][ct] = (floatx4){0.f, 0.f, 0.f, 0.f};

  // A staging: thread t covers row t>>2 (0..127), 8 cols at (t&3)*8 within the 32-wide K slice
  const int srow = t >> 2;
  const int scol8 = (t & 3) * 8;
  const int grow = (M0 + srow < N) ? (M0 + srow) : (N - 1);
  const float* xp = x + (size_t)grow * F + scol8;

  // B fragment chunk base (g-rotated)
  const int mb = cq + m + 2 * g;    // + ct*16, & 255 at use
  const int ldsw = (w << 6);        // wave's 64-chunk segment base

  // ---- prologue: stage kt=0 into buf 0 ----
  {
#pragma unroll
    for (int i = 0; i < 2; ++i)
      gl_lds16(Bt + (((size_t)(i * 512 + t)) << 3),
               &sm.B[0][(size_t)(i * 512 + ldsw) << 3]);
    float4 a0 = ld4(xp), a1 = ld4(xp + 4);
    ushort4 p0, p1;
    p0.x = f2bf(a0.x); p0.y = f2bf(a0.y); p0.z = f2bf(a0.z); p0.w = f2bf(a0.w);
    p1.x = f2bf(a1.x); p1.y = f2bf(a1.y); p1.z = f2bf(a1.z); p1.w = f2bf(a1.w);
    *(ushort4*)(sm.A[0] + srow * 40 + scol8) = p0;
    *(ushort4*)(sm.A[0] + srow * 40 + scol8 + 4) = p1;
  }
  __syncthreads();   // drains vmcnt (incl. gload_lds) + lgkmcnt

#pragma unroll 2
  for (int kt = 0; kt < 16; ++kt) {
    const int cur = kt & 1, nxt = cur ^ 1;
    float4 a0, a1;
    const bool more = (kt + 1 < 16);
    if (more) {
      // issue next B tile (async to LDS) and next A slice (to regs)
#pragma unroll
      for (int i = 0; i < 2; ++i)
        gl_lds16(Bt + (((size_t)(kt + 1) * 1024 + i * 512 + t) << 3),
                 &sm.B[nxt][(size_t)(i * 512 + ldsw) << 3]);
      a0 = ld4(xp + (kt + 1) * 32);
      a1 = ld4(xp + (kt + 1) * 32 + 4);
    }
    // compute current tile
    {
      const unsigned short* Ab = sm.A[cur];
      const unsigned short* Bb = sm.B[cur];
      short8 af[2], bf[8];
#pragma unroll
      for (int rt = 0; rt < 2; ++rt)
        af[rt] = *(const short8*)(Ab + (rq + rt * 16 + m) * 40 + g * 8);
#pragma unroll
      for (int ct = 0; ct < 8; ++ct) {
        const int chunk = g * 256 + ((mb + ct * 16) & 255);
        bf[ct] = *(const short8*)(Bb + ((size_t)chunk << 3));
      }
#pragma unroll
      for (int rt = 0; rt < 2; ++rt)
#pragma unroll
        for (int ct = 0; ct < 8; ++ct)
          acc[rt][ct] = __builtin_amdgcn_mfma_f32_16x16x32_bf16(af[rt], bf[ct], acc[rt][ct], 0, 0, 0);
    }
    if (more) {
      ushort4 p0, p1;
      p0.x = f2bf(a0.x); p0.y = f2bf(a0.y); p0.z = f2bf(a0.z); p0.w = f2bf(a0.w);
      p1.x = f2bf(a1.x); p1.y = f2bf(a1.y); p1.z = f2bf(a1.z); p1.w = f2bf(a1.w);
      *(ushort4*)(sm.A[nxt] + srow * 40 + scol8) = p0;
      *(ushort4*)(sm.A[nxt] + srow * 40 + scol8 + 4) = p1;
    }
    __syncthreads();   // single drain per K-step: buf[nxt] complete, buf[cur] free
  }

  // ---- epilogue, fully in-register. C/D layout: col = ct*16+m, row = rt*16+g*4+r ----
  if (cq == 0) {
    // ht half: bias + LN + relu; wave holds the FULL 128-col row -> shfl reduce
    float bt_l[8], lng_l[8], lnb_l[8];
#pragma unroll
    for (int ct = 0; ct < 8; ++ct) {
      bt_l[ct] = bt[ct * 16 + m];
      lng_l[ct] = lng[ct * 16 + m];
      lnb_l[ct] = lnb[ct * 16 + m];
    }
#pragma unroll
    for (int rt = 0; rt < 2; ++rt) {
#pragma unroll
      for (int r = 0; r < 4; ++r) {
        float sum = 0.f, sq = 0.f;
#pragma unroll
        for (int ct = 0; ct < 8; ++ct) {
          float v = acc[rt][ct][r] + bt_l[ct];
          acc[rt][ct][r] = v;
          sum += v; sq += v * v;
        }
        // reduce across the 16-lane m-group (masks 1,2,4,8 stay within group)
#pragma unroll
        for (int off = 1; off < 16; off <<= 1) {
          sum += __shfl_xor(sum, off, 64);
          sq  += __shfl_xor(sq,  off, 64);
        }
        const float mu = sum * (1.f / H);
        const float rs = rsqrtf(sq * (1.f / H) - mu * mu + EPS);
        const int row = M0 + rq + rt * 16 + g * 4 + r;
        if (row < N) {
          float* hp = ht + (size_t)row * H + m;
#pragma unroll
          for (int ct = 0; ct < 8; ++ct) {
            float o = (acc[rt][ct][r] - mu) * rs * lng_l[ct] + lnb_l[ct];
            hp[ct * 16] = o > 0.f ? o : 0.f;
          }
        }
      }
    }
  } else {
    // hg half: bias + BN + relu, elementwise
#pragma unroll
    for (int ct = 0; ct < 8; ++ct) {
      const int c2 = ct * 16 + m;
      const float s1 = IBN * bng[c2], b0 = bgv[c2], b2v = bnb[c2];
#pragma unroll
      for (int rt = 0; rt < 2; ++rt) {
#pragma unroll
        for (int r = 0; r < 4; ++r) {
          const int row = M0 + rq + rt * 16 + g * 4 + r;
          if (row < N) {
            float v = (acc[rt][ct][r] + b0) * s1 + b2v;
            hg[(size_t)row * H + c2] = v > 0.f ? v : 0.f;
          }
        }
      }
    }
  }
}

// ---------------- K2: gram + colsum partials, NO atomics ----------------
__global__ __launch_bounds__(256) void k2_gram(const float* __restrict__ ht,
                                               float* __restrict__ gp,   // [NB_GRAM][16384]
                                               float* __restrict__ sp)   // [NB_GRAM][128]
{
  const int t = threadIdx.x;
  const int b = blockIdx.x;
  const int base = b * 256;
  const int nend = (base + 256 < N) ? base + 256 : N;
  const int r0 = (t >> 4) * 8;
  const int c0 = (t & 15) * 8;
  float acc[8][8] = {};
  float colacc[8] = {};
  const bool do_col = (t < 16);
  int n = base;
  for (; n + 1 < nend; n += 2) {
    const float* hp0 = ht + (size_t)n * H;
    const float* hp1 = hp0 + H;
    float4 a00 = ld4(hp0 + r0), a01 = ld4(hp0 + r0 + 4);
    float4 b00 = ld4(hp0 + c0), b01 = ld4(hp0 + c0 + 4);
    float4 a10 = ld4(hp1 + r0), a11 = ld4(hp1 + r0 + 4);
    float4 b10 = ld4(hp1 + c0), b11 = ld4(hp1 + c0 + 4);
    float a0[8] = {a00.x, a00.y, a00.z, a00.w, a01.x, a01.y, a01.z, a01.w};
    float b0[8] = {b00.x, b00.y, b00.z, b00.w, b01.x, b01.y, b01.z, b01.w};
    float a1[8] = {a10.x, a10.y, a10.z, a10.w, a11.x, a11.y, a11.z, a11.w};
    float b1[8] = {b10.x, b10.y, b10.z, b10.w, b11.x, b11.y, b11.z, b11.w};
    if (do_col) {
#pragma unroll
      for (int j = 0; j < 8; ++j) colacc[j] += b0[j] + b1[j];
    }
#pragma unroll
    for (int i = 0; i < 8; ++i)
#pragma unroll
      for (int j = 0; j < 8; ++j)
        acc[i][j] += a0[i] * b0[j] + a1[i] * b1[j];
  }
  if (n < nend) {
    const float* hp0 = ht + (size_t)n * H;
    float4 a00 = ld4(hp0 + r0), a01 = ld4(hp0 + r0 + 4);
    float4 b00 = ld4(hp0 + c0), b01 = ld4(hp0 + c0 + 4);
    float a0[8] = {a00.x, a00.y, a00.z, a00.w, a01.x, a01.y, a01.z, a01.w};
    float b0[8] = {b00.x, b00.y, b00.z, b00.w, b01.x, b01.y, b01.z, b01.w};
    if (do_col) {
#pragma unroll
      for (int j = 0; j < 8; ++j) colacc[j] += b0[j];
    }
#pragma unroll
    for (int i = 0; i < 8; ++i)
#pragma unroll
      for (int j = 0; j < 8; ++j)
        acc[i][j] += a0[i] * b0[j];
  }
  float* g = gp + (size_t)b * 16384;
#pragma unroll
  for (int i = 0; i < 8; ++i) {
    st4(&g[(r0 + i) * H + c0], make_float4(acc[i][0], acc[i][1], acc[i][2], acc[i][3]));
    st4(&g[(r0 + i) * H + c0 + 4], make_float4(acc[i][4], acc[i][5], acc[i][6], acc[i][7]));
  }
  if (do_col) {
    float* spb = sp + (size_t)b * 128;
    st4(&spb[c0], make_float4(colacc[0], colacc[1], colacc[2], colacc[3]));
    st4(&spb[c0 + 4], make_float4(colacc[4], colacc[5], colacc[6], colacc[7]));
  }
}

// ---------------- K2r: reduce partials -> G, s ----------------
__global__ __launch_bounds__(256) void k2r_reduce(const float* __restrict__ gp,
    const float* __restrict__ sp, float* __restrict__ G, float* __restrict__ s)
{
  const int i = blockIdx.x * 256 + threadIdx.x;   // < 16384
  float s0 = 0.f, s1 = 0.f, s2 = 0.f, s3 = 0.f;
  int b = 0;
  for (; b + 3 < NB_GRAM; b += 4) {
    s0 += gp[(size_t)b * 16384 + i];
    s1 += gp[(size_t)(b + 1) * 16384 + i];
    s2 += gp[(size_t)(b + 2) * 16384 + i];
    s3 += gp[(size_t)(b + 3) * 16384 + i];
  }
  for (; b < NB_GRAM; ++b) s0 += gp[(size_t)b * 16384 + i];
  G[i] = (s0 + s1) + (s2 + s3);
  if (blockIdx.x == 0 && threadIdx.x < 128) {
    float t0 = 0.f, t1 = 0.f;
    int bb = 0;
    for (; bb + 1 < NB_GRAM; bb += 2) {
      t0 += sp[(size_t)bb * 128 + threadIdx.x];
      t1 += sp[(size_t)(bb + 1) * 128 + threadIdx.x];
    }
    for (; bb < NB_GRAM; ++bb) t0 += sp[(size_t)bb * 128 + threadIdx.x];
    s[threadIdx.x] = t0 + t1;
  }
}

// ---------------- K3a: GW = G @ {Wv, Wk, Wq} ----------------
__global__ __launch_bounds__(256) void k3a_gw(const float* __restrict__ G,
    const float* __restrict__ Wv, const float* __restrict__ Wk,
    const float* __restrict__ Wq, float* __restrict__ GW)
{
  const int flat = blockIdx.x * 256 + threadIdx.x;   // < 98304
  const int w = flat >> 15;
  const int rem = flat & 32767;
  const int i = rem >> 8;
  const int j = rem & 255;
  const float* W = (w == 0) ? Wv : (w == 1) ? Wk : Wq;
  float sum = 0.f;
#pragma unroll 8
  for (int k = 0; k < H; ++k) sum += G[i * H + k] * W[k * 256 + j];
  GW[flat] = sum;
}

// ---------------- K3k: ksum/vsum/qsum = s @ W + N*b ----------------
__global__ __launch_bounds__(256) void k3k_sums(const float* __restrict__ s,
    const float* __restrict__ Wk, const float* __restrict__ bk,
    const float* __restrict__ Wv, const float* __restrict__ bv,
    const float* __restrict__ Wq, const float* __restrict__ bq,
    float* __restrict__ ksum, float* __restrict__ vsum, float* __restrict__ qsum)
{
  const int flat = blockIdx.x * 256 + threadIdx.x;   // < 768
  const int w = flat >> 8;
  const int j = flat & 255;
  const float* W = (w == 0) ? Wk : (w == 1) ? Wv : Wq;
  const float* b = (w == 0) ? bk : (w == 1) ? bv : bq;
  float* out = (w == 0) ? ksum : (w == 1) ? vsum : qsum;
  float sum = 0.f;
#pragma unroll 8
  for (int k = 0; k < H; ++k) sum += s[k] * W[k * 256 + j];
  out[j] = sum + NF * b[j];
}

// ---------------- K3b: kv_raw[h,m,d] ----------------
__global__ __launch_bounds__(256) void k3b_kv(const float* __restrict__ GWv,
    const float* __restrict__ s, const float* __restrict__ Wk,
    const float* __restrict__ bk, const float* __restrict__ bv,
    const float* __restrict__ vsum, float* __restrict__ kv)
{
  const int flat = blockIdx.x * 256 + threadIdx.x;   // < 32768
  const int h = flat >> 14;
  const int m = (flat >> 7) & 127;
  const int d = flat & 127;
  float s1 = 0.f, s2 = 0.f;
#pragma unroll 4
  for (int k = 0; k < H; ++k) {
    float wkv = Wk[k * 256 + h * 128 + m];
    s1 += wkv * GWv[k * 256 + h * 128 + d];
    s2 += wkv * s[k];
  }
  kv[flat] = s1 + s2 * bv[h * 128 + d] + bk[h * 128 + m] * vsum[h * 128 + d];
}

// ---------------- K3c: ssq_q, ssq_k, inv ----------------
__global__ __launch_bounds__(256) void k3c_ssq(
    const float* __restrict__ Wk, const float* __restrict__ GWk,
    const float* __restrict__ Wq, const float* __restrict__ GWq,
    const float* __restrict__ bk, const float* __restrict__ ksum,
    const float* __restrict__ bq, const float* __restrict__ qsum,
    float* __restrict__ sc)
{
  __shared__ float red[512];
  const int t = threadIdx.x;
  float pk = 0.f, pq = 0.f;
  for (int i = t; i < 32768; i += 256) {
    pk += Wk[i] * GWk[i];
    pq += Wq[i] * GWq[i];
  }
  pk += 2.f * bk[t] * ksum[t] - NF * bk[t] * bk[t];
  pq += 2.f * bq[t] * qsum[t] - NF * bq[t] * bq[t];
  red[t] = pk; red[256 + t] = pq;
  __syncthreads();
  for (int off = 128; off > 0; off >>= 1) {
    if (t < off) { red[t] += red[t + off]; red[256 + t] += red[256 + t + off]; }
    __syncthreads();
  }
  if (t == 0) {
    float ssq_k = red[0], ssq_q = red[256];
    sc[0] = ssq_q; sc[1] = ssq_k;
    sc[2] = rsqrtf(ssq_q * ssq_k);   // 1/(||q|| * ||k||)
  }
}

// ---------------- K3d: B = Wq @ kv * inv + N*Wv -> packed bf16 Bt2[n=256][k=128] ----------------
__global__ __launch_bounds__(256) void k3d_B(const float* __restrict__ Wq,
    const float* __restrict__ kv, const float* __restrict__ Wv,
    const float* __restrict__ sc, unsigned short* __restrict__ Bt2)
{
  const int flat = blockIdx.x * 256 + threadIdx.x;   // < 32768
  const int i = flat >> 8;       // 0..127 : k-dim (h index)
  const int j = flat & 255;      // 0..255 : col (head*128 + d)
  const int h = j >> 7;
  const int d = j & 127;
  const float inv = sc[2];
  float sum = 0.f;
#pragma unroll 4
  for (int m = 0; m < H; ++m)
    sum += Wq[i * 256 + h * 128 + m] * kv[h * 16384 + m * 128 + d];
  Bt2[(size_t)j * H + i] = f2bf(sum * inv + NF * Wv[i * 256 + j]);
}

// ---------------- K3e: c, u, u0 ----------------
__global__ __launch_bounds__(512) void k3e_small(const float* __restrict__ bq,
    const float* __restrict__ kv, const float* __restrict__ bv,
    const float* __restrict__ Wq, const float* __restrict__ ksum,
    const float* __restrict__ sc, float* __restrict__ cc,
    float* __restrict__ u, float* __restrict__ u0)
{
  const int t = threadIdx.x;
  const float inv = sc[2];
  if (t < 256) {
    const int h = t >> 7, d = t & 127;
    float sum = 0.f;
    for (int m = 0; m < H; ++m) sum += bq[h * 128 + m] * kv[h * 16384 + m * 128 + d];
    cc[t] = sum * inv + NF * bv[t];
  } else {
    const int q = t - 256;
    const int i = q >> 1, h = q & 1;
    float sum = 0.f;
    for (int m = 0; m < H; ++m) sum += Wq[i * 256 + h * 128 + m] * ksum[h * 128 + m];
    u[i * 2 + h] = sum * inv;
  }
  if (t < 2) {
    float sum = 0.f;
    for (int m = 0; m < H; ++m) sum += bq[t * 128 + m] * ksum[t * 128 + m];
    u0[t] = sum * inv + NF;
  }
}

// ---------------- K4: MFMA attention apply + residual + LN -> x1 (in-place in ht) ----------------
// 64-row tile; 4 waves; each wave: 16 rows x all 256 cols (head combine is in-lane: ct vs ct+8)
__global__ __launch_bounds__(256) void k4_mfma(float* __restrict__ ht,
    const unsigned short* __restrict__ Bt2, const float* __restrict__ cc,
    const float* __restrict__ u, const float* __restrict__ u0,
    const float* __restrict__ lng, const float* __restrict__ lnb)
{
  __shared__ __align__(16) union {
    unsigned short A[64 * 136];       // 17408 B (bf16 ht tile)
    float lns[64 * 132];              // 33792 B (LN staging)
  } sm;
  __shared__ float u_s[256];
  __shared__ float rden_s[128];       // [row][head]
  __shared__ float mu_s[64], rs_s[64];
  const int t = threadIdx.x;
  const int lane = t & 63;
  const int w = t >> 6;
  const int rq = w * 16;              // wave row base 0/16/32/48
  const int g = lane >> 4;
  const int m = lane & 15;
  const int M0 = blockIdx.x * 64;

  // stage A: ht rows fp32 -> bf16 LDS (K=128 fits entirely)
  {
    const int srow = t >> 2;          // 0..63
    const int scol = (t & 3) * 32;    // 0,32,64,96
    const int grow = (M0 + srow < N) ? (M0 + srow) : (N - 1);
    const float* xp = ht + (size_t)grow * H + scol;
#pragma unroll
    for (int j = 0; j < 8; ++j) {
      float4 a4 = ld4(xp + j * 4);
      ushort4 p;
      p.x = f2bf(a4.x); p.y = f2bf(a4.y); p.z = f2bf(a4.z); p.w = f2bf(a4.w);
      *(ushort4*)(sm.A + srow * 136 + scol + j * 4) = p;
    }
  }
  u_s[t] = u[t];
  __syncthreads();

  floatx4 acc[16];
#pragma unroll
  for (int ct = 0; ct < 16; ++ct) acc[ct] = (floatx4){0.f, 0.f, 0.f, 0.f};
#pragma unroll
  for (int kk = 0; kk < 128; kk += 32) {
    short8 af = *(const short8*)(sm.A + (rq + m) * 136 + kk + g * 8);
#pragma unroll
    for (int ct = 0; ct < 16; ++ct) {
      short8 bf = *(const short8*)(Bt2 + (size_t)(ct * 16 + m) * H + kk + g * 8);
      acc[ct] = __builtin_amdgcn_mfma_f32_16x16x32_bf16(af, bf, acc[ct], 0, 0, 0);
    }
  }
  // denominators (waves 0,1): row=t>>1, head=t&1
  if (t < 128) {
    const int row = t >> 1, head = t & 1;
    float den = u0[head];
    for (int k = 0; k < H; ++k)
      den += bf2f(sm.A[row * 136 + k]) * u_s[k * 2 + head];
    rden_s[row * 2 + head] = 0.5f / den;   // mean-over-heads folded
  }
  __syncthreads();   // A fully consumed; lns may now overwrite the union

  // combine heads + residual -> lns
#pragma unroll
  for (int ct = 0; ct < 8; ++ct) {
    const int d = ct * 16 + m;
    const float c0v = cc[d], c1v = cc[128 + d];
#pragma unroll
    for (int r = 0; r < 4; ++r) {
      const int row = rq + g * 4 + r;         // block-local 0..63
      const int grow = M0 + row;
      const float rd0 = rden_s[row * 2], rd1 = rden_s[row * 2 + 1];
      float attn = (acc[ct][r] + c0v) * rd0 + (acc[ct + 8][r] + c1v) * rd1;
      float hres = (grow < N) ? ht[(size_t)grow * H + d] : 0.f;
      sm.lns[row * 132 + d] = (attn + hres) * 0.5f;
    }
  }
  __syncthreads();
  if (t < 64) {
    float sum = 0.f, sq = 0.f;
    for (int c2 = 0; c2 < H; ++c2) {
      float v = sm.lns[t * 132 + c2];
      sum += v; sq += v * v;
    }
    float mu = sum * (1.f / H);
    float var = sq * (1.f / H) - mu * mu;
    mu_s[t] = mu; rs_s[t] = rsqrtf(var + EPS);
  }
  __syncthreads();
  {
    const int r = t >> 2;
    const int cb = (t & 3) * 32;
    if (M0 + r < N) {
      const float mu = mu_s[r], rs = rs_s[r];
#pragma unroll
      for (int j = 0; j < 8; ++j) {
        const int c = cb + j * 4;
        float o[4];
#pragma unroll
        for (int q = 0; q < 4; ++q) {
          float v = (sm.lns[r * 132 + c + q] - mu) * rs * lng[c + q] + lnb[c + q];
          o[q] = v > 0.f ? v : 0.f;
        }
        st4(ht + (size_t)(M0 + r) * H + c, make_float4(o[0], o[1], o[2], o[3]));
      }
    }
  }
}

// ---------------- K5: in-degree (int counts) ----------------
__global__ __launch_bounds__(256) void k5_deg(const int* __restrict__ ei,
                                              int* __restrict__ cnt)
{
  const int i = blockIdx.x * 256 + threadIdx.x;
  if (i < E) atomicAdd(&cnt[ei[E + i]], 1);
}

// ---------------- scan1: per-1024-chunk sums ----------------
__global__ __launch_bounds__(256) void k_scan1(const int* __restrict__ cnt,
                                               int* __restrict__ bsum)
{
  __shared__ int red[256];
  const int t = threadIdx.x;
  const int base = blockIdx.x * 1024 + t * 4;
  int s = 0;
#pragma unroll
  for (int j = 0; j < 4; ++j) {
    int idx = base + j;
    if (idx < N) s += cnt[idx];
  }
  red[t] = s;
  __syncthreads();
  for (int off = 128; off > 0; off >>= 1) {
    if (t < off) red[t] += red[t + off];
    __syncthreads();
  }
  if (t == 0) bsum[blockIdx.x] = red[0];
}

// ---------------- scan2: parallel exclusive scan of 98 block sums ----------------
__global__ __launch_bounds__(128) void k_scan2(int* __restrict__ bsum)
{
  __shared__ int sh[128];
  const int t = threadIdx.x;
  const int v = (t < NB1024) ? bsum[t] : 0;
  sh[t] = v;
  __syncthreads();
  for (int off = 1; off < 128; off <<= 1) {
    int add = (t >= off) ? sh[t - off] : 0;
    __syncthreads();
    sh[t] += add;
    __syncthreads();
  }
  if (t < NB1024) bsum[t] = sh[t] - v;   // exclusive
}

// ---------------- scan3: intra-chunk exclusive scan -> ptr, cur ----------------
__global__ __launch_bounds__(256) void k_scan3(const int* __restrict__ cnt,
    const int* __restrict__ bsum, int* __restrict__ ptr, int* __restrict__ cur)
{
  __shared__ int part[256];
  const int t = threadIdx.x;
  const int base = blockIdx.x * 1024 + t * 4;
  int v[4];
  int tsum = 0;
#pragma unroll
  for (int j = 0; j < 4; ++j) {
    int idx = base + j;
    v[j] = (idx < N) ? cnt[idx] : 0;
    tsum += v[j];
  }
  part[t] = tsum;
  __syncthreads();
  for (int off = 1; off < 256; off <<= 1) {
    int add = (t >= off) ? part[t - off] : 0;
    __syncthreads();
    part[t] += add;
    __syncthreads();
  }
  int run = bsum[blockIdx.x] + part[t] - tsum;
#pragma unroll
  for (int j = 0; j < 4; ++j) {
    int idx = base + j;
    if (idx < N) { ptr[idx] = run; cur[idx] = run; }
    run += v[j];
  }
}

// ---------------- K6a: place edges into destination buckets ----------------
__global__ __launch_bounds__(256) void k6a_place(const int* __restrict__ ei,
    const int* __restrict__ cnt, int* __restrict__ cur,
    int* __restrict__ srow, float* __restrict__ sval)
{
  const int e = blockIdx.x * 256 + threadIdx.x;
  if (e >= E) return;
  const int r = ei[e];
  const int c = ei[E + e];
  const int p = atomicAdd(&cur[c], 1);
  srow[p] = r;
  const int dr = cnt[r];
  const float dv = (float)dr * (float)cnt[c];
  sval[p] = (dr > 0) ? rsqrtf(dv) : 0.f;   // nan_to_num(inf)=0 when deg[row]==0
}

// ---------------- K6b: gather-accumulate agg[n] = sum val*hg[row], 4-deep MLP ----------------
__global__ __launch_bounds__(256) void k6b_gather(const int* __restrict__ ptr,
    const int* __restrict__ cnt, const int* __restrict__ srow,
    const float* __restrict__ sval, const float* __restrict__ hg,
    float* __restrict__ agg)
{
  const int t = threadIdx.x;
  const int n = blockIdx.x * 8 + (t >> 5);     // 8 nodes per block
  const int lane4 = (t & 31) * 4;
  const int start = ptr[n];
  const int end = start + cnt[n];
  float4 acc = make_float4(0.f, 0.f, 0.f, 0.f);
  int e = start;
  for (; e + 3 < end; e += 4) {
    int r0 = srow[e], r1 = srow[e + 1], r2 = srow[e + 2], r3 = srow[e + 3];
    float v0 = sval[e], v1 = sval[e + 1], v2 = sval[e + 2], v3 = sval[e + 3];
    float4 h0 = ld4(hg + (size_t)r0 * H + lane4);
    float4 h1 = ld4(hg + (size_t)r1 * H + lane4);
    float4 h2 = ld4(hg + (size_t)r2 * H + lane4);
    float4 h3 = ld4(hg + (size_t)r3 * H + lane4);
    acc.x += v0 * h0.x + v1 * h1.x + v2 * h2.x + v3 * h3.x;
    acc.y += v0 * h0.y + v1 * h1.y + v2 * h2.y + v3 * h3.y;
    acc.z += v0 * h0.z + v1 * h1.z + v2 * h2.z + v3 * h3.z;
    acc.w += v0 * h0.w + v1 * h1.w + v2 * h2.w + v3 * h3.w;
  }
  for (; e < end; ++e) {
    int r0 = srow[e];
    float v0 = sval[e];
    float4 h0 = ld4(hg + (size_t)r0 * H + lane4);
    acc.x += v0 * h0.x;
    acc.y += v0 * h0.y;
    acc.z += v0 * h0.z;
    acc.w += v0 * h0.w;
  }
  st4(agg + (size_t)n * H + lane4, acc);
}

// ---------------- K78: MFMA fused conv+BN+relu+residual+blend+output GEMM ----------------
// 64-row tile, 4 waves x 16 rows. Phase 1: x2 = relu(BN(agg@Wc+cb)) + hg (conv MFMA
// from bf16 LDS agg x L2-resident Wcp). Phase 2: blend 0.2*ht+0.8*x2 -> bf16 LDS
// (reusing the agg buffer), out = blend @ fcp + fcB (MFMA).
__global__ __launch_bounds__(256) void k78_mfma(const float* __restrict__ agg,
    const float* __restrict__ hg, const unsigned short* __restrict__ Wcp,
    const float* __restrict__ cb, const float* __restrict__ g1,
    const float* __restrict__ b1, const float* __restrict__ ht,
    const unsigned short* __restrict__ fcp, const float* __restrict__ fcB,
    float* __restrict__ out)
{
  __shared__ __align__(16) unsigned short A1[64 * 136];   // 17408 B; agg tile, then x12 tile
  const int t = threadIdx.x;
  const int lane = t & 63;
  const int w = t >> 6;
  const int rq = w * 16;              // wave row base 0/16/32/48
  const int g = lane >> 4;
  const int m = lane & 15;
  const int M0 = blockIdx.x * 64;

  // stage agg rows fp32 -> bf16 LDS (coalesced)
  {
    const int srow = t >> 2;          // 0..63
    const int scol = (t & 3) * 32;    // 0,32,64,96
    const int grow = (M0 + srow < N) ? (M0 + srow) : (N - 1);
    const float* xp = agg + (size_t)grow * H + scol;
#pragma unroll
    for (int j = 0; j < 8; ++j) {
      float4 a4 = ld4(xp + j * 4);
      ushort4 p;
      p.x = f2bf(a4.x); p.y = f2bf(a4.y); p.z = f2bf(a4.z); p.w = f2bf(a4.w);
      *(ushort4*)(A1 + srow * 136 + scol + j * 4) = p;
    }
  }
  __syncthreads();

  // conv MFMA: 16 rows x 128 cols per wave
  floatx4 acc[8];
#pragma unroll
  for (int ct = 0; ct < 8; ++ct) acc[ct] = (floatx4){0.f, 0.f, 0.f, 0.f};
#pragma unroll
  for (int kk = 0; kk < 128; kk += 32) {
    short8 af = *(const short8*)(A1 + (rq + m) * 136 + kk + g * 8);
#pragma unroll
    for (int ct = 0; ct < 8; ++ct) {
      short8 bf = *(const short8*)(Wcp + (size_t)(ct * 16 + m) * H + kk + g * 8);
      acc[ct] = __builtin_amdgcn_mfma_f32_16x16x32_bf16(af, bf, acc[ct], 0, 0, 0);
    }
  }
  __syncthreads();   // all waves done reading A1; safe to overwrite with x12

  // epilogue: x12 = 0.2*x1 + 0.8*(relu(BN(acc+cb)) + hg) -> bf16 into A1
  // C/D layout: col = ct*16+m, row(block-local) = rq + g*4 + r
#pragma unroll
  for (int ct = 0; ct < 8; ++ct) {
    const int col = ct * 16 + m;
    const float s1 = IBN * g1[col], b0 = cb[col], b2v = b1[col];
#pragma unroll
    for (int r = 0; r < 4; ++r) {
      const int row = rq + g * 4 + r;
      const int grow = M0 + row;
      float v = (acc[ct][r] + b0) * s1 + b2v;
      v = v > 0.f ? v : 0.f;
      float x1v = 0.f, hgv = 0.f;
      if (grow < N) {
        x1v = ht[(size_t)grow * H + col];
        hgv = hg[(size_t)grow * H + col];
      }
      A1[row * 136 + col] = f2bf(0.2f * x1v + 0.8f * (v + hgv));
    }
  }
  __syncthreads();

  // out MFMA: 16 rows x 64 cols per wave
  floatx4 acc2[4];
#pragma unroll
  for (int ct = 0; ct < 4; ++ct) acc2[ct] = (floatx4){0.f, 0.f, 0.f, 0.f};
#pragma unroll
  for (int kk = 0; kk < 128; kk += 32) {
    short8 af = *(const short8*)(A1 + (rq + m) * 136 + kk + g * 8);
#pragma unroll
    for (int ct = 0; ct < 4; ++ct) {
      short8 bf = *(const short8*)(fcp + (size_t)(ct * 16 + m) * H + kk + g * 8);
      acc2[ct] = __builtin_amdgcn_mfma_f32_16x16x32_bf16(af, bf, acc2[ct], 0, 0, 0);
    }
  }
#pragma unroll
  for (int ct = 0; ct < 4; ++ct) {
    const int col = ct * 16 + m;
    const float bb = fcB[col];
#pragma unroll
    for (int r = 0; r < 4; ++r) {
      const int grow = M0 + rq + g * 4 + r;
      if (grow < N) out[(size_t)grow * C + col] = acc2[ct][r] + bb;
    }
  }
}

// ---------------- launch ----------------
extern "C" void kernel_launch(void* const* d_in, const int* in_sizes, int n_in,
                              void* d_out, int out_size, void* d_ws, size_t ws_size,
                              hipStream_t stream) {
  (void)in_sizes; (void)n_in; (void)out_size; (void)ws_size;
  const float* x       = (const float*)d_in[0];
  const int*   ei      = (const int*)d_in[1];
  const float* t_fc_w  = (const float*)d_in[2];
  const float* t_fc_b  = (const float*)d_in[3];
  const float* t_ln0_g = (const float*)d_in[4];
  const float* t_ln0_b = (const float*)d_in[5];
  const float* t_wq_w  = (const float*)d_in[6];
  const float* t_wq_b  = (const float*)d_in[7];
  const float* t_wk_w  = (const float*)d_in[8];
  const float* t_wk_b  = (const float*)d_in[9];
  const float* t_wv_w  = (const float*)d_in[10];
  const float* t_wv_b  = (const float*)d_in[11];
  const float* t_ln1_g = (const float*)d_in[12];
  const float* t_ln1_b = (const float*)d_in[13];
  const float* g_fc_w  = (const float*)d_in[14];
  const float* g_fc_b  = (const float*)d_in[15];
  const float* g_bn0_g = (const float*)d_in[16];
  const float* g_bn0_b = (const float*)d_in[17];
  const float* g_cv_w  = (const float*)d_in[18];
  const float* g_cv_b  = (const float*)d_in[19];
  const float* g_bn1_g = (const float*)d_in[20];
  const float* g_bn1_b = (const float*)d_in[21];
  const float* fc_w    = (const float*)d_in[22];
  const float* fc_b    = (const float*)d_in[23];

  float* W    = (float*)d_ws;
  float* ht   = W + OFF_HT;
  float* hg   = W + OFF_HG;
  float* agg  = W + OFF_AGG;       // first: gram partials; then: gather output
  int*   cnt  = (int*)(W + OFF_CNT);
  float* s    = W + OFF_S;
  float* G    = W + OFF_G;
  int*   ptr  = (int*)(W + OFF_PTR);
  int*   cur  = (int*)(W + OFF_CUR);
  int*   bsum = (int*)(W + OFF_BS);
  int*   srow = (int*)(W + OFF_SROW);
  float* sval = W + OFF_SVAL;
  float* gw   = W + OFF_GWV;
  float* kv   = W + OFF_KV;
  float* ksum = W + OFF_KSUM;
  float* vsum = W + OFF_VSUM;
  float* qsum = W + OFF_QSUM;
  float* sc   = W + OFF_SC;
  unsigned short* Bt2 = (unsigned short*)(W + OFF_B);
  float* cc   = W + OFF_CC;
  float* u    = W + OFF_U;
  float* u0   = W + OFF_U0;
  unsigned short* Bt  = (unsigned short*)(W + OFF_BT);
  unsigned short* Wcp = (unsigned short*)(W + OFF_WCP);
  unsigned short* fcp = (unsigned short*)(W + OFF_FCP);

  hipMemsetAsync(cnt, 0, N * sizeof(int), stream);

  // weight packs
  k0_cvt<<<512, 256, 0, stream>>>(t_fc_w, g_fc_w, Bt);
  k0b_cvt<<<96, 256, 0, stream>>>(g_cv_w, fc_w, Wcp, fcp);

  // graph branch CSR build (independent of k1)
  k5_deg<<<(E + 255) / 256, 256, 0, stream>>>(ei, cnt);
  k_scan1<<<NB1024, 256, 0, stream>>>(cnt, bsum);
  k_scan2<<<1, 128, 0, stream>>>(bsum);
  k_scan3<<<NB1024, 256, 0, stream>>>(cnt, bsum, ptr, cur);
  k6a_place<<<E / 256, 256, 0, stream>>>(ei, cnt, cur, srow, sval);

  k1_mfma<<<(N + 127) / 128, 512, 0, stream>>>(x, Bt, t_fc_b, t_ln0_g, t_ln0_b,
                                               g_fc_b, g_bn0_g, g_bn0_b, ht, hg);
  // trans reductions FIRST (partials live in agg, freed before gather overwrites)
  k2_gram<<<NB_GRAM, 256, 0, stream>>>(ht, agg, agg + SP_BASE);
  k2r_reduce<<<64, 256, 0, stream>>>(agg, agg + SP_BASE, G, s);
  // graph aggregation (gather) — overwrites agg
  k6b_gather<<<N / 8, 256, 0, stream>>>(ptr, cnt, srow, sval, hg, agg);
  k3a_gw<<<384, 256, 0, stream>>>(G, t_wv_w, t_wk_w, t_wq_w, gw);
  k3k_sums<<<3, 256, 0, stream>>>(s, t_wk_w, t_wk_b, t_wv_w, t_wv_b, t_wq_w, t_wq_b,
                                  ksum, vsum, qsum);
  k3b_kv<<<128, 256, 0, stream>>>(gw, s, t_wk_w, t_wk_b, t_wv_b, vsum, kv);
  k3c_ssq<<<1, 256, 0, stream>>>(t_wk_w, gw + 32768, t_wq_w, gw + 65536,
                                 t_wk_b, ksum, t_wq_b, qsum, sc);
  k3d_B<<<128, 256, 0, stream>>>(t_wq_w, kv, t_wv_w, sc, Bt2);
  k3e_small<<<1, 512, 0, stream>>>(t_wq_b, kv, t_wv_b, t_wq_w, ksum, sc, cc, u, u0);
  k4_mfma<<<(N + 63) / 64, 256, 0, stream>>>(ht, Bt2, cc, u, u0, t_ln1_g, t_ln1_b);
  // fused graph tail + output (MFMA)
  k78_mfma<<<(N + 63) / 64, 256, 0, stream>>>(agg, hg, Wcp, g_cv_b, g_bn1_g, g_bn1_b,
                                              ht, fcp, fc_b, (float*)d_out);
}